// Round 5
// baseline (1046.397 us; speedup 1.0000x reference)
//
#include <hip/hip_runtime.h>
#include <stdint.h>

#define Bn 64
#define Tn 400
#define Hn 512
#define En 256
#define Vn 50000
#define NOOVn 100
#define TPn 50
#define H2n 1024
#define VEXTn (Vn+NOOVn)  // 50100

typedef __bf16 bf16x8 __attribute__((ext_vector_type(8)));
typedef float  f32x4  __attribute__((ext_vector_type(4)));

__device__ __forceinline__ float sigf(float x){ return 1.0f/(1.0f+__expf(-x)); }
__device__ __forceinline__ float tanh_fast(float x){
  float e = __expf(2.0f*x);
  return (e-1.0f)/(e+1.0f);
}

__device__ __forceinline__ unsigned short f2bf(float f){
  union { float f; uint32_t u; } v; v.f = f;
  uint32_t r = v.u + 0x7FFFu + ((v.u >> 16) & 1u);
  return (unsigned short)(r >> 16);
}
__device__ __forceinline__ float bf2f(unsigned short s){
  union { uint32_t u; float f; } v; v.u = ((uint32_t)s) << 16;
  return v.f;
}

__device__ __forceinline__ void async16(const void* g, void* l){
  __builtin_amdgcn_global_load_lds((__attribute__((address_space(1))) void*)g,
                                   (__attribute__((address_space(3))) void*)l, 16, 0, 0);
}

// ---------------- front mega-launch ----------------
// [0,25600): enc fp32->bf16
// [25600,27648): Bt[n][k] = W[k][n] transpose+convert (We_h | Ws_h)
// [27648,27712): gemv_x full-K (single writer)          [verified r4: h,c exact]
// [27712,34112): prev_s copy (tau<50) into o_prevs [64][51][512]
__global__ __launch_bounds__(256) void k_front(const float* __restrict__ enc, unsigned short* __restrict__ enc_bf,
                                               const float* __restrict__ W1, const float* __restrict__ W2,
                                               unsigned short* __restrict__ Bt,
                                               const float* __restrict__ x_t, const float* __restrict__ ct_e,
                                               const float* __restrict__ W_xc, float* __restrict__ x_acc,
                                               const float* __restrict__ prev_s, float* __restrict__ o_prevs){
  __shared__ float tile[32][33];
  const int bx = blockIdx.x, tid = threadIdx.x;
  if (bx < 25600){
    int i = bx*256 + tid;
    float4 v = ((const float4*)enc)[i];
    ushort4 r;
    r.x = f2bf(v.x); r.y = f2bf(v.y); r.z = f2bf(v.z); r.w = f2bf(v.w);
    ((ushort4*)enc_bf)[i] = r;
    return;
  }
  if (bx < 27648){
    int t = bx - 25600;
    const float* W = (t >> 10) ? W2 : W1;
    int nbase = (t >> 10) * 1024;
    int rem = t & 1023;
    int n0 = (rem & 31)*32, k0 = (rem >> 5)*32;
    int tx = tid & 31, ty = tid >> 5;
    for (int i = 0; i < 32; i += 8)
      tile[ty+i][tx] = W[(size_t)(k0+ty+i)*1024 + n0+tx];
    __syncthreads();
    for (int i = 0; i < 32; i += 8)
      Bt[(size_t)(nbase+n0+ty+i)*1024 + k0+tx] = f2bf(tile[tx][ty+i]);
    return;
  }
  if (bx < 27712){
    int b = bx - 27648;
    int n = tid;
    float acc = 0.f;
    #pragma unroll 4
    for (int k = 0; k < 1280; ++k){
      float a = (k < 256) ? x_t[b*256+k] : ct_e[b*1024 + k - 256];
      acc += a * W_xc[(size_t)k*256 + n];
    }
    x_acc[b*256+n] = acc;
    return;
  }
  {
    int i = (bx - 27712)*256 + tid;       // [0, 1638400)
    int b = i / 25600;
    int rem = i - b*25600;                // tau*512 + j
    o_prevs[((size_t)b*51)*512 + rem] = prev_s[i];
  }
}

// gates full-K, single writer  [verified r4]
__global__ __launch_bounds__(256) void k_gates(const float* __restrict__ x_acc, const float* __restrict__ b_xc,
                                               const float* __restrict__ s_h,
                                               const float* __restrict__ W_ih, const float* __restrict__ W_hh,
                                               float* __restrict__ gates_acc){
  int x = blockIdx.x & 7, b = blockIdx.x >> 3;
  int n = x*256 + threadIdx.x;
  float acc = 0.f;
  #pragma unroll 4
  for (int k = 0; k < 768; ++k){
    float a; const float* wrow;
    if (k < 256){ a = x_acc[b*256+k] + b_xc[k]; wrow = &W_ih[(size_t)k*2048]; }
    else        { a = s_h[b*512 + k-256];       wrow = &W_hh[(size_t)(k-256)*2048]; }
    acc += a * wrow[n];
  }
  gates_acc[(size_t)b*2048 + n] = acc;
}

// lstm activations + h-append to o_prevs tail  [verified r4]
__global__ __launch_bounds__(256) void k_lstm(const float* __restrict__ gates_acc,
                                              const float* __restrict__ b_ih, const float* __restrict__ b_hh,
                                              const float* __restrict__ s_c,
                                              float* __restrict__ h_out, float* __restrict__ c_out,
                                              float* __restrict__ o_prevs){
  int b = blockIdx.x >> 1;
  int j = (blockIdx.x & 1)*256 + threadIdx.x;
  const float* g = &gates_acc[(size_t)b*2048];
  float gi = g[j]      + b_ih[j]      + b_hh[j];
  float gf = g[512+j]  + b_ih[512+j]  + b_hh[512+j];
  float gg = g[1024+j] + b_ih[1024+j] + b_hh[1024+j];
  float go = g[1536+j] + b_ih[1536+j] + b_hh[1536+j];
  float c = sigf(gf)*s_c[b*512+j] + sigf(gi)*tanh_fast(gg);
  float h = sigf(go)*tanh_fast(c);
  h_out[b*512+j] = h;
  c_out[b*512+j] = c;
  o_prevs[((size_t)b*51 + 50)*512 + j] = h;
}

// qe + qd + outvec z0 (all depend only on h/c)
// [0,256): qe full-K; [256,384): qd full-K; [384,512): ov z0 (atomicAdd onto zeroed ov_acc)
__global__ __launch_bounds__(256) void k_qq(const float* __restrict__ h, const float* __restrict__ c,
                                            const float* __restrict__ We_s, float* __restrict__ qe_acc,
                                            const float* __restrict__ Wd_s, float* __restrict__ qd_acc,
                                            const float* __restrict__ W_V, float* __restrict__ ov_acc){
  const int bx = blockIdx.x, tid = threadIdx.x;
  if (bx < 256){
    int x = bx & 3, b = bx >> 2;
    int n = x*256 + tid;
    float acc = 0.f;
    #pragma unroll 4
    for (int k = 0; k < 1024; ++k){
      float a = (k < 512) ? h[b*512+k] : c[b*512 + k-512];
      acc += a * We_s[(size_t)k*1024 + n];
    }
    qe_acc[b*1024+n] = acc;
  } else if (bx < 384){
    int j = bx - 256;
    int x = j & 1, b = j >> 1;
    int n = x*256 + tid;
    float acc = 0.f;
    #pragma unroll 4
    for (int k = 0; k < 512; ++k)
      acc += h[b*512+k] * Wd_s[(size_t)k*512 + n];
    qd_acc[b*512+n] = acc;
  } else {
    int j = bx - 384;
    int x = j & 1, b = j >> 1;
    int n = x*256 + tid;
    float acc = 0.f;
    #pragma unroll 4
    for (int k = 0; k < 512; ++k)
      acc += h[b*512+k] * W_V[(size_t)k*512 + n];    // z=0 rows [0,512)
    atomicAdd(&ov_acc[b*512+n], acc);
  }
}

// ---------------- the big fused dual-GEMM (EXACT round-3 verified version) ----------------
// [0,256): intra-decoder ed GEMM; [256,3456): 128^2 MFMA tiles, bijective XCD swizzle.
// et_raw/au_raw/et2_acc all atomicAdd onto memset-zeroed buffers (two wn-waves per tile
// each hold a 64-column half-sum -> MUST be summed atomically; r4's plain store raced).
__global__ __launch_bounds__(256,4) void k_gemm_big(
    const unsigned short* __restrict__ Abf,   // [25600][1024]
    const unsigned short* __restrict__ Btbf,  // [2048][1024]
    const float* __restrict__ q_e,
    const float* __restrict__ be_s,
    const float* __restrict__ bs_h, const float* __restrict__ ve,
    const float* __restrict__ vs1,  const float* __restrict__ vs2,
    float* __restrict__ et_raw, float* __restrict__ au_raw, float* __restrict__ et2_acc,
    const float* __restrict__ prev_s, const float* __restrict__ Wd_prev,
    const float* __restrict__ q_d, const float* __restrict__ bd_s,
    const float* __restrict__ vd, float* __restrict__ tmp_ed)
{
  __shared__ __align__(16) unsigned short As[128*64];
  __shared__ __align__(16) unsigned short Bs[128*64];
  __shared__ float bias2_s[2][128];
  __shared__ float vv_s[128];
  __shared__ float rowW_s[128];
  __shared__ unsigned char rowSel_s[128];

  const int tid = threadIdx.x;
  const int linb = blockIdx.x;

  if (linb < 256){
    int b = linb >> 2, ex = linb & 3;
    int j = (ex & 1)*256 + tid;
    int taub = (ex >> 1)*25;
    float acc[25];
    #pragma unroll
    for (int t = 0; t < 25; ++t) acc[t] = 0.f;
    const float* ps = &prev_s[((size_t)b*50 + taub)*512];
    for (int k = 0; k < 512; ++k){
      float wv = Wd_prev[(size_t)k*512 + j];
      #pragma unroll
      for (int t = 0; t < 25; ++t) acc[t] += ps[(size_t)t*512 + k] * wv;
    }
    float qv = q_d[b*512+j] + bd_s[j], vdj = vd[j];
    #pragma unroll
    for (int t = 0; t < 25; ++t)
      tmp_ed[((size_t)b*50 + taub + t)*512 + j] = tanh_fast(acc[t] + qv) * vdj;
    return;
  }

  const int g = linb - 256;                       // 0..3199 = 8*400
  const int swz = (g & 7)*400 + (g >> 3);         // bijective XCD chunk swizzle
  const int bn = swz & 15, bm = swz >> 4;

  const int r0  = bm*128;
  const int n0g = bn*128;
  const bool etmode = (n0g < 1024);
  const int dbase = etmode ? n0g : (n0g - 1024);
  const int b_lo = r0/400;
  const int b_hi = min(b_lo+1, 63);
  const bool bcross = (r0/400) != ((r0+127)/400);

  if (tid < 128){
    int r = r0 + tid;
    int bb = r/400;
    rowSel_s[tid] = (unsigned char)(bb - b_lo);
    rowW_s[tid]   = vs2[r - bb*400];
    vv_s[tid]     = etmode ? ve[dbase+tid] : vs1[dbase+tid];
    bias2_s[0][tid] = etmode ? (q_e[b_lo*1024 + dbase + tid] + be_s[dbase+tid]) : bs_h[dbase+tid];
    bias2_s[1][tid] = etmode ? (q_e[b_hi*1024 + dbase + tid] + be_s[dbase+tid]) : bs_h[dbase+tid];
  }

  const int w = tid >> 6, lane = tid & 63;
  const int wm = w & 1, wn = w >> 1;
  const int lr = lane & 15, lq = lane >> 4;

  const int srow = lane >> 3;
  const int c_g  = (lane & 7) ^ (srow & 7);
  const unsigned short* gA0 = Abf  + (size_t)(r0  + w*32 + srow)*1024 + c_g*8;
  const unsigned short* gB0 = Btbf + (size_t)(n0g + w*32 + srow)*1024 + c_g*8;
  unsigned short* lA0 = As + w*32*64;
  unsigned short* lB0 = Bs + w*32*64;

  f32x4 acc[4][4];
  #pragma unroll
  for (int i = 0; i < 4; ++i)
    #pragma unroll
    for (int j = 0; j < 4; ++j){ acc[i][j][0]=0.f; acc[i][j][1]=0.f; acc[i][j][2]=0.f; acc[i][j][3]=0.f; }

  for (int kt = 0; kt < 16; ++kt){
    __syncthreads();
    #pragma unroll
    for (int q = 0; q < 4; ++q){
      async16(gA0 + (size_t)q*8*1024 + kt*64, lA0 + q*512);
      async16(gB0 + (size_t)q*8*1024 + kt*64, lB0 + q*512);
    }
    __syncthreads();
    #pragma unroll
    for (int kk = 0; kk < 2; ++kk){
      const int slot8 = ((kk*4 + lq) ^ (lr & 7)) * 8;
      bf16x8 a[4], b[4];
      #pragma unroll
      for (int i = 0; i < 4; ++i){
        a[i] = *(const bf16x8*)&As[(wm*64 + i*16 + lr)*64 + slot8];
        b[i] = *(const bf16x8*)&Bs[(wn*64 + i*16 + lr)*64 + slot8];
      }
      #pragma unroll
      for (int mt = 0; mt < 4; ++mt)
        #pragma unroll
        for (int nt = 0; nt < 4; ++nt)
          acc[mt][nt] = __builtin_amdgcn_mfma_f32_16x16x32_bf16(a[mt], b[nt], acc[mt][nt], 0, 0, 0);
    }
  }

  // ---- register epilogue ----
  float vvr[4], bias0[4], bias1[4];
  #pragma unroll
  for (int nt = 0; nt < 4; ++nt){
    int n = wn*64 + nt*16 + lr;
    vvr[nt]   = vv_s[n];
    bias0[nt] = bias2_s[0][n];
    bias1[nt] = bias2_s[1][n];
  }

  float rowdot[16];
  float colacc[4][2];
  #pragma unroll
  for (int nt = 0; nt < 4; ++nt){ colacc[nt][0]=0.f; colacc[nt][1]=0.f; }

  #pragma unroll
  for (int mt = 0; mt < 4; ++mt){
    #pragma unroll
    for (int v = 0; v < 4; ++v){
      int m = wm*64 + mt*16 + lq*4 + v;
      int sel = rowSel_s[m];
      float rw = rowW_s[m];
      float rd = 0.f;
      #pragma unroll
      for (int nt = 0; nt < 4; ++nt){
        float t = tanh_fast(acc[mt][nt][v] + (sel ? bias1[nt] : bias0[nt]));
        rd += t * vvr[nt];
        if (!etmode) colacc[nt][sel] += t * rw;
      }
      rowdot[mt*4+v] = rd;
    }
  }

  #pragma unroll
  for (int i = 0; i < 16; ++i){
    float s = rowdot[i];
    s += __shfl_xor(s,1); s += __shfl_xor(s,2); s += __shfl_xor(s,4); s += __shfl_xor(s,8);
    rowdot[i] = s;
  }
  if (lr == 0){
    float* dst = etmode ? et_raw : au_raw;
    #pragma unroll
    for (int i = 0; i < 16; ++i){
      int m = wm*64 + (i>>2)*16 + lq*4 + (i&3);
      atomicAdd(&dst[r0+m], rowdot[i]);
    }
  }

  if (!etmode){
    #pragma unroll
    for (int nt = 0; nt < 4; ++nt){
      #pragma unroll
      for (int s = 0; s < 2; ++s){
        float c = colacc[nt][s];
        c += __shfl_xor(c,16); c += __shfl_xor(c,32);
        if (lq == 0 && (s == 0 || bcross)){
          int n = wn*64 + nt*16 + lr;
          atomicAdd(&et2_acc[(b_lo+s)*1024 + dbase + n], c);
        }
      }
    }
  }
}

// ---------------- attention normalizations (EXACT round-3 verified version) ----------------
__global__ __launch_bounds__(512) void k_attn_norm(const float* __restrict__ et_raw, const float* __restrict__ au_raw,
                                                   const float* __restrict__ et2_acc,
                                                   const float* __restrict__ sumts, const float* __restrict__ mask,
                                                   float* __restrict__ o_sumn, float* __restrict__ o_au,
                                                   float* __restrict__ o_et2, float* __restrict__ at_ws){
  int b = blockIdx.x, tid = threadIdx.x;
  __shared__ float red[512];
  float w = 0.f;
  if (tid < 400){
    float e  = __expf(et_raw[b*400+tid]);
    float st = sumts[b*400+tid];
    o_sumn[b*400+tid] = st + e;
    w = (e/st) * mask[b*400+tid];
  }
  red[tid] = w; __syncthreads();
  for (int s = 256; s > 0; s >>= 1){ if (tid < s) red[tid] += red[tid+s]; __syncthreads(); }
  float invw = 1.0f/red[0];
  __syncthreads();
  if (tid < 400) at_ws[b*400+tid] = w*invw;

  float a = 0.f;
  if (tid < 400) a = sigf(au_raw[b*400+tid]) * mask[b*400+tid];
  red[tid] = a; __syncthreads();
  for (int s = 256; s > 0; s >>= 1){ if (tid < s) red[tid] += red[tid+s]; __syncthreads(); }
  float inva = 1.0f/red[0];
  if (tid < 400) o_au[b*400+tid] = a*inva;

  for (int d = tid; d < 1024; d += 512) o_et2[b*1024+d] = sigf(et2_acc[b*1024+d]);
}

// cte (+ outvec z4/z5 siblings)  [verified r4]
// [0,128): cte; [128,256): z4; [256,384): z5
__global__ __launch_bounds__(256) void k_cte_ov(const unsigned short* __restrict__ Abf, const float* __restrict__ at_ws,
                                                float* __restrict__ o_cte, const float* __restrict__ o_et2,
                                                const float* __restrict__ W_V, float* __restrict__ ov_acc){
  const int bx = blockIdx.x, tid = threadIdx.x;
  if (bx < 128){
    int x = bx & 1, b = bx >> 1;
    int d0 = (x*256 + tid)*2;
    float a0 = 0.f, a1 = 0.f;
    for (int t = 0; t < 400; ++t){
      float w = at_ws[b*400+t];
      uint32_t v = *(const uint32_t*)&Abf[((size_t)(b*400+t))*1024 + d0];
      a0 += w * bf2f((unsigned short)(v & 0xffffu));
      a1 += w * bf2f((unsigned short)(v >> 16));
    }
    float2 r; r.x = a0; r.y = a1;
    *(float2*)&o_cte[b*1024 + d0] = r;
    return;
  }
  int zz = (bx < 256) ? 0 : 1;                     // z4 or z5
  int j = bx - 128 - zz*128;
  int x = j & 1, b = j >> 1;
  int n = x*256 + tid;
  const float* base = &o_et2[b*1024 + zz*512];
  const float* wrow = &W_V[(size_t)(2048 + zz*512)*512];
  float acc = 0.f;
  #pragma unroll 4
  for (int k = 0; k < 512; ++k)
    acc += base[k] * wrow[(size_t)k*512 + n];
  atomicAdd(&ov_acc[b*512+n], acc);
}

// ctd + p_gen + outvec z3 (in-block) + outvec z1/z2 (sibling blocks)  [verified r4]
// [0,64): ctd_pgen(+z3); [64,128): z1; [128,192): z2. 512 threads.
__global__ __launch_bounds__(512) void k_ctd_ov(const float* __restrict__ tmp_ed, const float* __restrict__ prev_s,
                                                const float* __restrict__ cte, const float* __restrict__ et2,
                                                const float* __restrict__ h, const float* __restrict__ c,
                                                const float* __restrict__ w_pg_cte, const float* __restrict__ w_pg_ctd,
                                                const float* __restrict__ w_pg_st, const float* __restrict__ w_pg_em,
                                                const float* __restrict__ b_pg_st,
                                                const float* __restrict__ W_V,
                                                float* __restrict__ ct_d, float* __restrict__ p_gen,
                                                float* __restrict__ ov_acc){
  const int bx = blockIdx.x, tid = threadIdx.x;
  if (bx >= 64){
    int zz = (bx < 128) ? 0 : 1;                   // z1 or z2
    int b = bx - 64 - zz*64;
    const float* base = &cte[b*1024 + zz*512];
    const float* wrow = &W_V[(size_t)(512 + zz*512)*512];
    float acc = 0.f;
    #pragma unroll 4
    for (int k = 0; k < 512; ++k)
      acc += base[k] * wrow[(size_t)k*512 + tid];
    atomicAdd(&ov_acc[b*512+tid], acc);
    return;
  }
  int b = bx;
  __shared__ float ed_s[50];
  __shared__ float ad_s[50];
  __shared__ float ctd_s[512];
  __shared__ float red[512];
  if (tid < 400){
    int tau = tid >> 3, part = tid & 7;
    const float* tp = &tmp_ed[((size_t)b*50 + tau)*512 + part*64];
    float p = 0.f;
    for (int j = 0; j < 64; ++j) p += tp[j];
    p += __shfl_xor(p, 1); p += __shfl_xor(p, 2); p += __shfl_xor(p, 4);
    if (part == 0) ed_s[tau] = p;
  }
  __syncthreads();
  if (tid == 0){
    float mx = -1e30f;
    for (int t = 0; t < 50; ++t) mx = fmaxf(mx, ed_s[t]);
    float se = 0.f;
    for (int t = 0; t < 50; ++t){ float e = __expf(ed_s[t]-mx); ad_s[t] = e; se += e; }
    float inv = 1.f/se;
    for (int t = 0; t < 50; ++t) ad_s[t] *= inv;
  }
  __syncthreads();
  float acc = 0.f;
  for (int t = 0; t < 50; ++t) acc += ad_s[t]*prev_s[((size_t)b*50 + t)*512 + tid];
  ct_d[b*512+tid] = acc;
  ctd_s[tid] = acc;

  // p_gen partials
  float s = acc*w_pg_ctd[tid] + h[b*512+tid]*w_pg_st[tid] + c[b*512+tid]*w_pg_st[512+tid];
  s += cte[b*1024+tid]*w_pg_cte[tid] + cte[b*1024+512+tid]*w_pg_cte[512+tid];
  s += et2[b*1024+tid]*w_pg_em[tid]  + et2[b*1024+512+tid]*w_pg_em[512+tid];
  red[tid] = s; __syncthreads();
  for (int k = 256; k > 0; k >>= 1){ if (tid < k) red[tid] += red[tid+k]; __syncthreads(); }
  if (tid == 0) p_gen[b] = sigf(red[0] + b_pg_st[0]);

  // outvec z3 using in-LDS ct_d
  float accv = 0.f;
  #pragma unroll 4
  for (int k = 0; k < 512; ++k)
    accv += ctd_s[k] * W_V[(size_t)(1536 + k)*512 + tid];
  atomicAdd(&ov_acc[b*512+tid], accv);
}

// ---------------- logits MFMA (fused A-convert + softmax partials)  [verified r4] ----------------
__global__ __launch_bounds__(256,4) void k_logits_mfma(const float* __restrict__ ov_acc,  // [64][512] fp32
                                                       const float* __restrict__ b_V,    // [512]
                                                       const float* __restrict__ W_V1,   // [512][50000] fp32
                                                       const float* __restrict__ b_V1, float* __restrict__ logits,
                                                       float* __restrict__ mpart, float* __restrict__ spart){
  __shared__ __align__(16) unsigned short As[64][72];
  __shared__ __align__(16) unsigned short Bs[64][72];
  __shared__ float pred[4][64];
  __shared__ float gmax[64];
  const int tid = threadIdx.x;
  const int n0 = blockIdx.x*64;
  const int w = tid >> 6, lane = tid & 63;
  const int lr = lane & 15, lq = lane >> 4;

  const int am = tid >> 2, ac = tid & 3;
  const int sn = tid & 63, skg = tid >> 6;
  const int bnc = (n0 + sn < Vn) ? (n0 + sn) : (Vn - 1);

  f32x4 acc[4];
  #pragma unroll
  for (int i = 0; i < 4; ++i){ acc[i][0]=0.f; acc[i][1]=0.f; acc[i][2]=0.f; acc[i][3]=0.f; }

  for (int kt = 0; kt < 8; ++kt){
    const int k0 = kt*64;
    __syncthreads();
    #pragma unroll
    for (int s = 0; s < 2; ++s){
      int ke = k0 + (ac + 4*s)*8;
      float4 fa  = *(const float4*)&ov_acc[am*512 + ke];
      float4 fa2 = *(const float4*)&ov_acc[am*512 + ke + 4];
      float4 fb  = *(const float4*)&b_V[ke];
      float4 fb2 = *(const float4*)&b_V[ke + 4];
      ushort4 u0, u1;
      u0.x = f2bf(fa.x+fb.x);  u0.y = f2bf(fa.y+fb.y);  u0.z = f2bf(fa.z+fb.z);  u0.w = f2bf(fa.w+fb.w);
      u1.x = f2bf(fa2.x+fb2.x); u1.y = f2bf(fa2.y+fb2.y); u1.z = f2bf(fa2.z+fb2.z); u1.w = f2bf(fa2.w+fb2.w);
      *(ushort4*)&As[am][(ac + 4*s)*8]     = u0;
      *(ushort4*)&As[am][(ac + 4*s)*8 + 4] = u1;
    }
    #pragma unroll
    for (int jq = 0; jq < 4; ++jq){
      int kb = k0 + skg*16 + jq*4;
      float f0 = W_V1[(size_t)(kb+0)*Vn + bnc];
      float f1 = W_V1[(size_t)(kb+1)*Vn + bnc];
      float f2 = W_V1[(size_t)(kb+2)*Vn + bnc];
      float f3 = W_V1[(size_t)(kb+3)*Vn + bnc];
      ushort4 u; u.x = f2bf(f0); u.y = f2bf(f1); u.z = f2bf(f2); u.w = f2bf(f3);
      *(ushort4*)&Bs[sn][skg*16 + jq*4] = u;
    }
    __syncthreads();
    #pragma unroll
    for (int kk = 0; kk < 2; ++kk){
      bf16x8 a[4], b;
      #pragma unroll
      for (int i = 0; i < 4; ++i)
        a[i] = *(const bf16x8*)&As[i*16 + lr][kk*32 + lq*8];
      b = *(const bf16x8*)&Bs[w*16 + lr][kk*32 + lq*8];
      #pragma unroll
      for (int mt = 0; mt < 4; ++mt)
        acc[mt] = __builtin_amdgcn_mfma_f32_16x16x32_bf16(a[mt], b, acc[mt], 0, 0, 0);
    }
  }

  const int n = n0 + w*16 + lr;
  const bool nok = (n < Vn);
  const float bb = nok ? b_V1[n] : 0.f;

  #pragma unroll
  for (int mt = 0; mt < 4; ++mt)
    #pragma unroll
    for (int v = 0; v < 4; ++v){
      int m = mt*16 + lq*4 + v;
      float val = nok ? (acc[mt][v] + bb) : -1e30f;
      if (nok) logits[(size_t)m*Vn + n] = val;
      float t = val;
      t = fmaxf(t, __shfl_xor(t,1)); t = fmaxf(t, __shfl_xor(t,2));
      t = fmaxf(t, __shfl_xor(t,4)); t = fmaxf(t, __shfl_xor(t,8));
      if (lr == 0) pred[w][m] = t;
    }
  __syncthreads();
  if (tid < 64)
    gmax[tid] = fmaxf(fmaxf(pred[0][tid], pred[1][tid]), fmaxf(pred[2][tid], pred[3][tid]));
  __syncthreads();

  #pragma unroll
  for (int mt = 0; mt < 4; ++mt)
    #pragma unroll
    for (int v = 0; v < 4; ++v){
      int m = mt*16 + lq*4 + v;
      float e = nok ? __expf(acc[mt][v] + bb - gmax[m]) : 0.f;
      e += __shfl_xor(e,1); e += __shfl_xor(e,2);
      e += __shfl_xor(e,4); e += __shfl_xor(e,8);
      if (lr == 0) pred[w][m] = e;
    }
  __syncthreads();
  if (tid < 64){
    float s = pred[0][tid] + pred[1][tid] + pred[2][tid] + pred[3][tid];
    mpart[(size_t)tid*782 + blockIdx.x] = gmax[tid];
    spart[(size_t)tid*782 + blockIdx.x] = s;
  }
}

// combine partials, write probs for a 6250-col slice, then scatter this chunk's indices  [verified r4]
__global__ __launch_bounds__(1024) void k_softmax_scatter(const float* __restrict__ logits,
                                                          const float* __restrict__ mpart, const float* __restrict__ spart,
                                                          const float* __restrict__ p_gen,
                                                          const int* __restrict__ ebev, const float* __restrict__ at_ws,
                                                          float* __restrict__ final_out){
  int b = blockIdx.y, ch = blockIdx.x, tid = threadIdx.x;
  __shared__ float red[1024];
  float mv = (tid < 782) ? mpart[(size_t)b*782 + tid] : -1e30f;
  red[tid] = mv; __syncthreads();
  for (int s = 512; s > 0; s >>= 1){ if (tid < s) red[tid] = fmaxf(red[tid], red[tid+s]); __syncthreads(); }
  float M = red[0]; __syncthreads();
  float sv = (tid < 782) ? spart[(size_t)b*782 + tid] * __expf(mv - M) : 0.f;
  red[tid] = sv; __syncthreads();
  for (int s = 512; s > 0; s >>= 1){ if (tid < s) red[tid] += red[tid+s]; __syncthreads(); }
  float pgb = p_gen[b];
  float scale = pgb/red[0];
  const float* lrow = &logits[(size_t)b*Vn];
  float* frow = &final_out[(size_t)b*VEXTn];
  int v0 = ch*6250;
  for (int v = v0 + tid; v < v0 + 6250; v += 1024) frow[v] = __expf(lrow[v] - M)*scale;
  if (ch == 7)
    for (int v = Vn + tid; v < VEXTn; v += 1024) frow[v] = 0.f;
  __syncthreads();
  int hi = (ch == 7) ? VEXTn : (v0 + 6250);
  if (tid < 400){
    int idx = ebev[b*400+tid];
    if (idx >= v0 && idx < hi){
      float add = (1.f - pgb) * at_ws[b*400+tid];
      atomicAdd(&frow[idx], add);
    }
  }
}

extern "C" void kernel_launch(void* const* d_in, const int* in_sizes, int n_in,
                              void* d_out, int out_size, void* d_ws, size_t ws_size,
                              hipStream_t stream)
{
  const float* x_t    = (const float*)d_in[0];
  const float* s_h    = (const float*)d_in[1];
  const float* s_c    = (const float*)d_in[2];
  const float* enc    = (const float*)d_in[3];
  const float* mask   = (const float*)d_in[4];
  const float* ct_e   = (const float*)d_in[5];
  const float* sumts  = (const float*)d_in[7];
  const float* prev_s = (const float*)d_in[8];
  const int*   ebev   = (const int*)d_in[9];
  const float* W_xc   = (const float*)d_in[10];
  const float* b_xc   = (const float*)d_in[11];
  const float* W_ih   = (const float*)d_in[12];
  const float* W_hh   = (const float*)d_in[13];
  const float* b_ih   = (const float*)d_in[14];
  const float* b_hh   = (const float*)d_in[15];
  const float* We_h   = (const float*)d_in[16];
  const float* We_s   = (const float*)d_in[17];
  const float* be_s   = (const float*)d_in[18];
  const float* ve     = (const float*)d_in[19];
  const float* Ws_h   = (const float*)d_in[20];
  const float* bs_h   = (const float*)d_in[21];
  const float* vs1    = (const float*)d_in[22];
  const float* vs2    = (const float*)d_in[23];
  const float* Wd_prev= (const float*)d_in[24];
  const float* Wd_s   = (const float*)d_in[25];
  const float* bd_s   = (const float*)d_in[26];
  const float* vd     = (const float*)d_in[27];
  const float* w_pg_em  = (const float*)d_in[28];
  const float* w_pg_cte = (const float*)d_in[29];
  const float* w_pg_ctd = (const float*)d_in[30];
  const float* w_pg_st  = (const float*)d_in[31];
  const float* b_pg_st  = (const float*)d_in[32];
  const float* W_V    = (const float*)d_in[33];
  const float* b_V    = (const float*)d_in[34];
  const float* W_V1   = (const float*)d_in[35];
  const float* b_V1   = (const float*)d_in[36];
  (void)in_sizes; (void)n_in; (void)out_size; (void)ws_size;

  float* out = (float*)d_out;
  float* o_final = out;
  float* o_h     = out + 3206400;
  float* o_c     = out + 3239168;
  float* o_cte   = out + 3271936;
  float* o_au    = out + 3337472;
  float* o_et2   = out + 3363072;
  float* o_sumn  = out + 3428608;
  float* o_prevs = out + 3454208;

  char* ws = (char*)d_ws;
  // memset-zeroed atomic accumulators (round-3 semantics)
  float* et_raw    = (float*)(ws + 0);          // 102400
  float* au_raw    = (float*)(ws + 102400);     // 102400
  float* et2_acc   = (float*)(ws + 204800);     // 262144
  float* ov_acc    = (float*)(ws + 466944);     // 131072 -> memset [0, 598016)
  // single-writer scratch
  float* x_acc     = (float*)(ws + 598016);     // 65536
  float* gates_acc = (float*)(ws + 663552);     // 524288
  float* qe_acc    = (float*)(ws + 1187840);    // 262144
  float* qd_acc    = (float*)(ws + 1449984);    // 131072
  float* at_ws   = (float*)(ws + 1581056);      // 102400
  float* ct_d    = (float*)(ws + 1683456);      // 131072
  float* p_gen   = (float*)(ws + 1814528);      // 4096
  float* tmp_ed  = (float*)(ws + 1818624);      // 6553600 -> 8372224
  float* mpart   = (float*)(ws + 8372224);      // 200192
  float* spart   = (float*)(ws + 8572416);      // 200192 -> 8772608
  unsigned short* enc_bf = (unsigned short*)(ws + 8772608);   // 52428800 -> 61201408
  float* logits  = (float*)(ws + 8772608);      // 12.8MB, overlays enc_bf AFTER cte (last reader)
  unsigned short* Bt_bf  = (unsigned short*)(ws + 61201408);  // 4194304 -> 65395712

  hipMemsetAsync(ws, 0, 598016, stream);
  k_front<<<34112, 256, 0, stream>>>(enc, enc_bf, We_h, Ws_h, Bt_bf,
                                     x_t, ct_e, W_xc, x_acc, prev_s, o_prevs);
  k_gates<<<512, 256, 0, stream>>>(x_acc, b_xc, s_h, W_ih, W_hh, gates_acc);
  k_lstm<<<128, 256, 0, stream>>>(gates_acc, b_ih, b_hh, s_c, o_h, o_c, o_prevs);
  k_qq<<<512, 256, 0, stream>>>(o_h, o_c, We_s, qe_acc, Wd_s, qd_acc, W_V, ov_acc);
  k_gemm_big<<<3456, 256, 0, stream>>>(enc_bf, Bt_bf, qe_acc, be_s, bs_h, ve, vs1, vs2,
                                       et_raw, au_raw, et2_acc,
                                       prev_s, Wd_prev, qd_acc, bd_s, vd, tmp_ed);
  k_attn_norm<<<64, 512, 0, stream>>>(et_raw, au_raw, et2_acc, sumts, mask, o_sumn, o_au, o_et2, at_ws);
  k_cte_ov<<<384, 256, 0, stream>>>(enc_bf, at_ws, o_cte, o_et2, W_V, ov_acc);
  k_ctd_ov<<<192, 512, 0, stream>>>(tmp_ed, prev_s, o_cte, o_et2, o_h, o_c,
                                    w_pg_cte, w_pg_ctd, w_pg_st, w_pg_em, b_pg_st,
                                    W_V, ct_d, p_gen, ov_acc);
  k_logits_mfma<<<782, 256, 0, stream>>>(ov_acc, b_V, W_V1, b_V1, logits, mpart, spart);
  k_softmax_scatter<<<dim3(8,64), 1024, 0, stream>>>(logits, mpart, spart, p_gen, ebev, at_ws, o_final);
}

// Round 6
// 737.819 us; speedup vs baseline: 1.4182x; 1.4182x over previous
//
#include <hip/hip_runtime.h>
#include <stdint.h>

#define Bn 64
#define Tn 400
#define Hn 512
#define En 256
#define Vn 50000
#define NOOVn 100
#define TPn 50
#define H2n 1024
#define VEXTn (Vn+NOOVn)  // 50100

typedef __bf16 bf16x8 __attribute__((ext_vector_type(8)));
typedef float  f32x4  __attribute__((ext_vector_type(4)));

__device__ __forceinline__ float sigf(float x){ return 1.0f/(1.0f+__expf(-x)); }
__device__ __forceinline__ float tanh_fast(float x){
  float e = __expf(2.0f*x);
  return (e-1.0f)/(e+1.0f);
}

__device__ __forceinline__ unsigned short f2bf(float f){
  union { float f; uint32_t u; } v; v.f = f;
  uint32_t r = v.u + 0x7FFFu + ((v.u >> 16) & 1u);
  return (unsigned short)(r >> 16);
}
__device__ __forceinline__ float bf2f(unsigned short s){
  union { uint32_t u; float f; } v; v.u = ((uint32_t)s) << 16;
  return v.f;
}

__device__ __forceinline__ void async16(const void* g, void* l){
  __builtin_amdgcn_global_load_lds((__attribute__((address_space(1))) void*)g,
                                   (__attribute__((address_space(3))) void*)l, 16, 0, 0);
}

// ---------------- front mega-launch ----------------
// Latency-bound gemv_x blocks FIRST (start at t=0, hide under conv traffic):
// [0,320): gemv_x split-K (z=bx>>6, K=256, atomics)   [r3-verified math]
// [320,25920): enc fp32->bf16
// [25920,27968): Bt[n][k] = W[k][n] transpose+convert
// [27968,34368): prev_s copy (tau<50) into o_prevs [64][51][512]
__global__ __launch_bounds__(256) void k_front(const float* __restrict__ enc, unsigned short* __restrict__ enc_bf,
                                               const float* __restrict__ W1, const float* __restrict__ W2,
                                               unsigned short* __restrict__ Bt,
                                               const float* __restrict__ x_t, const float* __restrict__ ct_e,
                                               const float* __restrict__ W_xc, float* __restrict__ x_acc,
                                               const float* __restrict__ prev_s, float* __restrict__ o_prevs){
  __shared__ float tile[32][33];
  const int bx = blockIdx.x, tid = threadIdx.x;
  if (bx < 320){
    int z = bx >> 6, b = bx & 63;
    int n = tid, k0 = z*256;
    float acc = 0.f;
    #pragma unroll 4
    for (int kk = 0; kk < 256; ++kk){
      int k = k0 + kk;
      float a = (k < 256) ? x_t[b*256+k] : ct_e[b*1024 + k - 256];
      acc += a * W_xc[(size_t)k*256 + n];
    }
    atomicAdd(&x_acc[b*256+n], acc);
    return;
  }
  if (bx < 25920){
    int i = (bx - 320)*256 + tid;
    float4 v = ((const float4*)enc)[i];
    ushort4 r;
    r.x = f2bf(v.x); r.y = f2bf(v.y); r.z = f2bf(v.z); r.w = f2bf(v.w);
    ((ushort4*)enc_bf)[i] = r;
    return;
  }
  if (bx < 27968){
    int t = bx - 25920;
    const float* W = (t >> 10) ? W2 : W1;
    int nbase = (t >> 10) * 1024;
    int rem = t & 1023;
    int n0 = (rem & 31)*32, k0 = (rem >> 5)*32;
    int tx = tid & 31, ty = tid >> 5;
    for (int i = 0; i < 32; i += 8)
      tile[ty+i][tx] = W[(size_t)(k0+ty+i)*1024 + n0+tx];
    __syncthreads();
    for (int i = 0; i < 32; i += 8)
      Bt[(size_t)(nbase+n0+ty+i)*1024 + k0+tx] = f2bf(tile[tx][ty+i]);
    return;
  }
  {
    int i = (bx - 27968)*256 + tid;       // [0, 1638400)
    int b = i / 25600;
    int rem = i - b*25600;                // tau*512 + j
    o_prevs[((size_t)b*51)*512 + rem] = prev_s[i];
  }
}

// gates split-K (z 0..2, K=256, atomics)  [r3-verified math]
__global__ __launch_bounds__(256) void k_gates(const float* __restrict__ x_acc, const float* __restrict__ b_xc,
                                               const float* __restrict__ s_h,
                                               const float* __restrict__ W_ih, const float* __restrict__ W_hh,
                                               float* __restrict__ gates_acc){
  int x = blockIdx.x & 7;
  int rem = blockIdx.x >> 3;
  int b = rem & 63, z = rem >> 6;        // z 0..2
  int n = x*256 + threadIdx.x;
  int k0 = z*256;
  float acc = 0.f;
  #pragma unroll 4
  for (int kk = 0; kk < 256; ++kk){
    int k = k0 + kk;
    float a; const float* wrow;
    if (k < 256){ a = x_acc[b*256+k] + b_xc[k]; wrow = &W_ih[(size_t)k*2048]; }
    else        { a = s_h[b*512 + k-256];       wrow = &W_hh[(size_t)(k-256)*2048]; }
    acc += a * wrow[n];
  }
  atomicAdd(&gates_acc[(size_t)b*2048 + n], acc);
}

// lstm activations + h-append to o_prevs tail  [verified r4/r5]
__global__ __launch_bounds__(256) void k_lstm(const float* __restrict__ gates_acc,
                                              const float* __restrict__ b_ih, const float* __restrict__ b_hh,
                                              const float* __restrict__ s_c,
                                              float* __restrict__ h_out, float* __restrict__ c_out,
                                              float* __restrict__ o_prevs){
  int b = blockIdx.x >> 1;
  int j = (blockIdx.x & 1)*256 + threadIdx.x;
  const float* g = &gates_acc[(size_t)b*2048];
  float gi = g[j]      + b_ih[j]      + b_hh[j];
  float gf = g[512+j]  + b_ih[512+j]  + b_hh[512+j];
  float gg = g[1024+j] + b_ih[1024+j] + b_hh[1024+j];
  float go = g[1536+j] + b_ih[1536+j] + b_hh[1536+j];
  float c = sigf(gf)*s_c[b*512+j] + sigf(gi)*tanh_fast(gg);
  float h = sigf(go)*tanh_fast(c);
  h_out[b*512+j] = h;
  c_out[b*512+j] = c;
  o_prevs[((size_t)b*51 + 50)*512 + j] = h;
}

// qe + qd + outvec z0, all split-K-256 with atomics (r3-verified parallelism)
// [0,1024): qe (x 0..3, b, z 0..3); [1024,1280): qd (x 0..1, b, z 0..1);
// [1280,1536): ov z0 (x 0..1, b, kh 0..1)
__global__ __launch_bounds__(256) void k_qq(const float* __restrict__ h, const float* __restrict__ c,
                                            const float* __restrict__ We_s, float* __restrict__ qe_acc,
                                            const float* __restrict__ Wd_s, float* __restrict__ qd_acc,
                                            const float* __restrict__ W_V, float* __restrict__ ov_acc){
  const int bx = blockIdx.x, tid = threadIdx.x;
  if (bx < 1024){
    int x = bx & 3, b = (bx >> 2) & 63, z = bx >> 8;
    int n = x*256 + tid, k0 = z*256;
    float acc = 0.f;
    #pragma unroll 4
    for (int kk = 0; kk < 256; ++kk){
      int k = k0 + kk;
      float a = (k < 512) ? h[b*512+k] : c[b*512 + k-512];
      acc += a * We_s[(size_t)k*1024 + n];
    }
    atomicAdd(&qe_acc[b*1024+n], acc);
  } else if (bx < 1280){
    int j = bx - 1024;
    int x = j & 1, b = (j >> 1) & 63, z = j >> 7;
    int n = x*256 + tid, k0 = z*256;
    float acc = 0.f;
    #pragma unroll 4
    for (int kk = 0; kk < 256; ++kk){
      int k = k0 + kk;
      acc += h[b*512+k] * Wd_s[(size_t)k*512 + n];
    }
    atomicAdd(&qd_acc[b*512+n], acc);
  } else {
    int j = bx - 1280;
    int x = j & 1, b = (j >> 1) & 63, kh = j >> 7;
    int n = x*256 + tid, k0 = kh*256;
    float acc = 0.f;
    #pragma unroll 4
    for (int kk = 0; kk < 256; ++kk){
      int k = k0 + kk;
      acc += h[b*512+k] * W_V[(size_t)k*512 + n];    // z=0 rows [0,512)
    }
    atomicAdd(&ov_acc[b*512+n], acc);
  }
}

// ---------------- the big fused dual-GEMM (EXACT round-3/5 verified version) ----------------
__global__ __launch_bounds__(256,4) void k_gemm_big(
    const unsigned short* __restrict__ Abf,   // [25600][1024]
    const unsigned short* __restrict__ Btbf,  // [2048][1024]
    const float* __restrict__ q_e,
    const float* __restrict__ be_s,
    const float* __restrict__ bs_h, const float* __restrict__ ve,
    const float* __restrict__ vs1,  const float* __restrict__ vs2,
    float* __restrict__ et_raw, float* __restrict__ au_raw, float* __restrict__ et2_acc,
    const float* __restrict__ prev_s, const float* __restrict__ Wd_prev,
    const float* __restrict__ q_d, const float* __restrict__ bd_s,
    const float* __restrict__ vd, float* __restrict__ tmp_ed)
{
  __shared__ __align__(16) unsigned short As[128*64];
  __shared__ __align__(16) unsigned short Bs[128*64];
  __shared__ float bias2_s[2][128];
  __shared__ float vv_s[128];
  __shared__ float rowW_s[128];
  __shared__ unsigned char rowSel_s[128];

  const int tid = threadIdx.x;
  const int linb = blockIdx.x;

  if (linb < 256){
    int b = linb >> 2, ex = linb & 3;
    int j = (ex & 1)*256 + tid;
    int taub = (ex >> 1)*25;
    float acc[25];
    #pragma unroll
    for (int t = 0; t < 25; ++t) acc[t] = 0.f;
    const float* ps = &prev_s[((size_t)b*50 + taub)*512];
    for (int k = 0; k < 512; ++k){
      float wv = Wd_prev[(size_t)k*512 + j];
      #pragma unroll
      for (int t = 0; t < 25; ++t) acc[t] += ps[(size_t)t*512 + k] * wv;
    }
    float qv = q_d[b*512+j] + bd_s[j], vdj = vd[j];
    #pragma unroll
    for (int t = 0; t < 25; ++t)
      tmp_ed[((size_t)b*50 + taub + t)*512 + j] = tanh_fast(acc[t] + qv) * vdj;
    return;
  }

  const int g = linb - 256;                       // 0..3199 = 8*400
  const int swz = (g & 7)*400 + (g >> 3);         // bijective XCD chunk swizzle
  const int bn = swz & 15, bm = swz >> 4;

  const int r0  = bm*128;
  const int n0g = bn*128;
  const bool etmode = (n0g < 1024);
  const int dbase = etmode ? n0g : (n0g - 1024);
  const int b_lo = r0/400;
  const int b_hi = min(b_lo+1, 63);
  const bool bcross = (r0/400) != ((r0+127)/400);

  if (tid < 128){
    int r = r0 + tid;
    int bb = r/400;
    rowSel_s[tid] = (unsigned char)(bb - b_lo);
    rowW_s[tid]   = vs2[r - bb*400];
    vv_s[tid]     = etmode ? ve[dbase+tid] : vs1[dbase+tid];
    bias2_s[0][tid] = etmode ? (q_e[b_lo*1024 + dbase + tid] + be_s[dbase+tid]) : bs_h[dbase+tid];
    bias2_s[1][tid] = etmode ? (q_e[b_hi*1024 + dbase + tid] + be_s[dbase+tid]) : bs_h[dbase+tid];
  }

  const int w = tid >> 6, lane = tid & 63;
  const int wm = w & 1, wn = w >> 1;
  const int lr = lane & 15, lq = lane >> 4;

  const int srow = lane >> 3;
  const int c_g  = (lane & 7) ^ (srow & 7);
  const unsigned short* gA0 = Abf  + (size_t)(r0  + w*32 + srow)*1024 + c_g*8;
  const unsigned short* gB0 = Btbf + (size_t)(n0g + w*32 + srow)*1024 + c_g*8;
  unsigned short* lA0 = As + w*32*64;
  unsigned short* lB0 = Bs + w*32*64;

  f32x4 acc[4][4];
  #pragma unroll
  for (int i = 0; i < 4; ++i)
    #pragma unroll
    for (int j = 0; j < 4; ++j){ acc[i][j][0]=0.f; acc[i][j][1]=0.f; acc[i][j][2]=0.f; acc[i][j][3]=0.f; }

  for (int kt = 0; kt < 16; ++kt){
    __syncthreads();
    #pragma unroll
    for (int q = 0; q < 4; ++q){
      async16(gA0 + (size_t)q*8*1024 + kt*64, lA0 + q*512);
      async16(gB0 + (size_t)q*8*1024 + kt*64, lB0 + q*512);
    }
    __syncthreads();
    #pragma unroll
    for (int kk = 0; kk < 2; ++kk){
      const int slot8 = ((kk*4 + lq) ^ (lr & 7)) * 8;
      bf16x8 a[4], b[4];
      #pragma unroll
      for (int i = 0; i < 4; ++i){
        a[i] = *(const bf16x8*)&As[(wm*64 + i*16 + lr)*64 + slot8];
        b[i] = *(const bf16x8*)&Bs[(wn*64 + i*16 + lr)*64 + slot8];
      }
      #pragma unroll
      for (int mt = 0; mt < 4; ++mt)
        #pragma unroll
        for (int nt = 0; nt < 4; ++nt)
          acc[mt][nt] = __builtin_amdgcn_mfma_f32_16x16x32_bf16(a[mt], b[nt], acc[mt][nt], 0, 0, 0);
    }
  }

  // ---- register epilogue ----
  float vvr[4], bias0[4], bias1[4];
  #pragma unroll
  for (int nt = 0; nt < 4; ++nt){
    int n = wn*64 + nt*16 + lr;
    vvr[nt]   = vv_s[n];
    bias0[nt] = bias2_s[0][n];
    bias1[nt] = bias2_s[1][n];
  }

  float rowdot[16];
  float colacc[4][2];
  #pragma unroll
  for (int nt = 0; nt < 4; ++nt){ colacc[nt][0]=0.f; colacc[nt][1]=0.f; }

  #pragma unroll
  for (int mt = 0; mt < 4; ++mt){
    #pragma unroll
    for (int v = 0; v < 4; ++v){
      int m = wm*64 + mt*16 + lq*4 + v;
      int sel = rowSel_s[m];
      float rw = rowW_s[m];
      float rd = 0.f;
      #pragma unroll
      for (int nt = 0; nt < 4; ++nt){
        float t = tanh_fast(acc[mt][nt][v] + (sel ? bias1[nt] : bias0[nt]));
        rd += t * vvr[nt];
        if (!etmode) colacc[nt][sel] += t * rw;
      }
      rowdot[mt*4+v] = rd;
    }
  }

  #pragma unroll
  for (int i = 0; i < 16; ++i){
    float s = rowdot[i];
    s += __shfl_xor(s,1); s += __shfl_xor(s,2); s += __shfl_xor(s,4); s += __shfl_xor(s,8);
    rowdot[i] = s;
  }
  if (lr == 0){
    float* dst = etmode ? et_raw : au_raw;
    #pragma unroll
    for (int i = 0; i < 16; ++i){
      int m = wm*64 + (i>>2)*16 + lq*4 + (i&3);
      atomicAdd(&dst[r0+m], rowdot[i]);
    }
  }

  if (!etmode){
    #pragma unroll
    for (int nt = 0; nt < 4; ++nt){
      #pragma unroll
      for (int s = 0; s < 2; ++s){
        float c = colacc[nt][s];
        c += __shfl_xor(c,16); c += __shfl_xor(c,32);
        if (lq == 0 && (s == 0 || bcross)){
          int n = wn*64 + nt*16 + lr;
          atomicAdd(&et2_acc[(b_lo+s)*1024 + dbase + n], c);
        }
      }
    }
  }
}

// ---------------- attention normalizations (verified) ----------------
__global__ __launch_bounds__(512) void k_attn_norm(const float* __restrict__ et_raw, const float* __restrict__ au_raw,
                                                   const float* __restrict__ et2_acc,
                                                   const float* __restrict__ sumts, const float* __restrict__ mask,
                                                   float* __restrict__ o_sumn, float* __restrict__ o_au,
                                                   float* __restrict__ o_et2, float* __restrict__ at_ws){
  int b = blockIdx.x, tid = threadIdx.x;
  __shared__ float red[512];
  float w = 0.f;
  if (tid < 400){
    float e  = __expf(et_raw[b*400+tid]);
    float st = sumts[b*400+tid];
    o_sumn[b*400+tid] = st + e;
    w = (e/st) * mask[b*400+tid];
  }
  red[tid] = w; __syncthreads();
  for (int s = 256; s > 0; s >>= 1){ if (tid < s) red[tid] += red[tid+s]; __syncthreads(); }
  float invw = 1.0f/red[0];
  __syncthreads();
  if (tid < 400) at_ws[b*400+tid] = w*invw;

  float a = 0.f;
  if (tid < 400) a = sigf(au_raw[b*400+tid]) * mask[b*400+tid];
  red[tid] = a; __syncthreads();
  for (int s = 256; s > 0; s >>= 1){ if (tid < s) red[tid] += red[tid+s]; __syncthreads(); }
  float inva = 1.0f/red[0];
  if (tid < 400) o_au[b*400+tid] = a*inva;

  for (int d = tid; d < 1024; d += 512) o_et2[b*1024+d] = sigf(et2_acc[b*1024+d]);
}

// cte (+ outvec z4/z5, split-K-256)
// [0,128): cte; [128,640): z4/z5: zz=idx>>8, kh=(idx&255)>>7, j=idx&127
__global__ __launch_bounds__(256) void k_cte_ov(const unsigned short* __restrict__ Abf, const float* __restrict__ at_ws,
                                                float* __restrict__ o_cte, const float* __restrict__ o_et2,
                                                const float* __restrict__ W_V, float* __restrict__ ov_acc){
  const int bx = blockIdx.x, tid = threadIdx.x;
  if (bx < 128){
    int x = bx & 1, b = bx >> 1;
    int d0 = (x*256 + tid)*2;
    float a0 = 0.f, a1 = 0.f;
    for (int t = 0; t < 400; ++t){
      float w = at_ws[b*400+t];
      uint32_t v = *(const uint32_t*)&Abf[((size_t)(b*400+t))*1024 + d0];
      a0 += w * bf2f((unsigned short)(v & 0xffffu));
      a1 += w * bf2f((unsigned short)(v >> 16));
    }
    float2 r; r.x = a0; r.y = a1;
    *(float2*)&o_cte[b*1024 + d0] = r;
    return;
  }
  int idx = bx - 128;                              // [0,512)
  int zz = idx >> 8;                               // z4 or z5
  int rem = idx & 255;
  int kh = rem >> 7;
  int j = rem & 127;
  int x = j & 1, b = j >> 1;
  int n = x*256 + tid;
  const float* base = &o_et2[b*1024 + zz*512];
  const float* wrow = &W_V[(size_t)(2048 + zz*512)*512];
  float acc = 0.f;
  #pragma unroll 4
  for (int kk = 0; kk < 256; ++kk){
    int k = kh*256 + kk;
    acc += base[k] * wrow[(size_t)k*512 + n];
  }
  atomicAdd(&ov_acc[b*512+n], acc);
}

// ctd + p_gen + outvec z3 (in-block) + outvec z1/z2 (split-K-256 siblings)
// [0,64): ctd_pgen(+z3); [64,320): z1/z2: zz=idx>>7, kh=(idx>>6)&1, b=idx&63. 512 threads.
__global__ __launch_bounds__(512) void k_ctd_ov(const float* __restrict__ tmp_ed, const float* __restrict__ prev_s,
                                                const float* __restrict__ cte, const float* __restrict__ et2,
                                                const float* __restrict__ h, const float* __restrict__ c,
                                                const float* __restrict__ w_pg_cte, const float* __restrict__ w_pg_ctd,
                                                const float* __restrict__ w_pg_st, const float* __restrict__ w_pg_em,
                                                const float* __restrict__ b_pg_st,
                                                const float* __restrict__ W_V,
                                                float* __restrict__ ct_d, float* __restrict__ p_gen,
                                                float* __restrict__ ov_acc){
  const int bx = blockIdx.x, tid = threadIdx.x;
  if (bx >= 64){
    int idx = bx - 64;                             // [0,256)
    int zz = idx >> 7;                             // z1 or z2
    int kh = (idx >> 6) & 1;
    int b = idx & 63;
    const float* base = &cte[b*1024 + zz*512];
    const float* wrow = &W_V[(size_t)(512 + zz*512)*512];
    float acc = 0.f;
    #pragma unroll 4
    for (int kk = 0; kk < 256; ++kk){
      int k = kh*256 + kk;
      acc += base[k] * wrow[(size_t)k*512 + tid];
    }
    atomicAdd(&ov_acc[b*512+tid], acc);
    return;
  }
  int b = bx;
  __shared__ float ed_s[50];
  __shared__ float ad_s[50];
  __shared__ float ctd_s[512];
  __shared__ float red[512];
  if (tid < 400){
    int tau = tid >> 3, part = tid & 7;
    const float* tp = &tmp_ed[((size_t)b*50 + tau)*512 + part*64];
    float p = 0.f;
    for (int j = 0; j < 64; ++j) p += tp[j];
    p += __shfl_xor(p, 1); p += __shfl_xor(p, 2); p += __shfl_xor(p, 4);
    if (part == 0) ed_s[tau] = p;
  }
  __syncthreads();
  if (tid == 0){
    float mx = -1e30f;
    for (int t = 0; t < 50; ++t) mx = fmaxf(mx, ed_s[t]);
    float se = 0.f;
    for (int t = 0; t < 50; ++t){ float e = __expf(ed_s[t]-mx); ad_s[t] = e; se += e; }
    float inv = 1.f/se;
    for (int t = 0; t < 50; ++t) ad_s[t] *= inv;
  }
  __syncthreads();
  float acc = 0.f;
  for (int t = 0; t < 50; ++t) acc += ad_s[t]*prev_s[((size_t)b*50 + t)*512 + tid];
  ct_d[b*512+tid] = acc;
  ctd_s[tid] = acc;

  // p_gen partials
  float s = acc*w_pg_ctd[tid] + h[b*512+tid]*w_pg_st[tid] + c[b*512+tid]*w_pg_st[512+tid];
  s += cte[b*1024+tid]*w_pg_cte[tid] + cte[b*1024+512+tid]*w_pg_cte[512+tid];
  s += et2[b*1024+tid]*w_pg_em[tid]  + et2[b*1024+512+tid]*w_pg_em[512+tid];
  red[tid] = s; __syncthreads();
  for (int k = 256; k > 0; k >>= 1){ if (tid < k) red[tid] += red[tid+k]; __syncthreads(); }
  if (tid == 0) p_gen[b] = sigf(red[0] + b_pg_st[0]);

  // outvec z3 using in-LDS ct_d
  float accv = 0.f;
  #pragma unroll 4
  for (int k = 0; k < 512; ++k)
    accv += ctd_s[k] * W_V[(size_t)(1536 + k)*512 + tid];
  atomicAdd(&ov_acc[b*512+tid], accv);
}

// ---------------- logits MFMA (fused A-convert + softmax partials)  [verified] ----------------
__global__ __launch_bounds__(256,4) void k_logits_mfma(const float* __restrict__ ov_acc,  // [64][512] fp32
                                                       const float* __restrict__ b_V,    // [512]
                                                       const float* __restrict__ W_V1,   // [512][50000] fp32
                                                       const float* __restrict__ b_V1, float* __restrict__ logits,
                                                       float* __restrict__ mpart, float* __restrict__ spart){
  __shared__ __align__(16) unsigned short As[64][72];
  __shared__ __align__(16) unsigned short Bs[64][72];
  __shared__ float pred[4][64];
  __shared__ float gmax[64];
  const int tid = threadIdx.x;
  const int n0 = blockIdx.x*64;
  const int w = tid >> 6, lane = tid & 63;
  const int lr = lane & 15, lq = lane >> 4;

  const int am = tid >> 2, ac = tid & 3;
  const int sn = tid & 63, skg = tid >> 6;
  const int bnc = (n0 + sn < Vn) ? (n0 + sn) : (Vn - 1);

  f32x4 acc[4];
  #pragma unroll
  for (int i = 0; i < 4; ++i){ acc[i][0]=0.f; acc[i][1]=0.f; acc[i][2]=0.f; acc[i][3]=0.f; }

  for (int kt = 0; kt < 8; ++kt){
    const int k0 = kt*64;
    __syncthreads();
    #pragma unroll
    for (int s = 0; s < 2; ++s){
      int ke = k0 + (ac + 4*s)*8;
      float4 fa  = *(const float4*)&ov_acc[am*512 + ke];
      float4 fa2 = *(const float4*)&ov_acc[am*512 + ke + 4];
      float4 fb  = *(const float4*)&b_V[ke];
      float4 fb2 = *(const float4*)&b_V[ke + 4];
      ushort4 u0, u1;
      u0.x = f2bf(fa.x+fb.x);  u0.y = f2bf(fa.y+fb.y);  u0.z = f2bf(fa.z+fb.z);  u0.w = f2bf(fa.w+fb.w);
      u1.x = f2bf(fa2.x+fb2.x); u1.y = f2bf(fa2.y+fb2.y); u1.z = f2bf(fa2.z+fb2.z); u1.w = f2bf(fa2.w+fb2.w);
      *(ushort4*)&As[am][(ac + 4*s)*8]     = u0;
      *(ushort4*)&As[am][(ac + 4*s)*8 + 4] = u1;
    }
    #pragma unroll
    for (int jq = 0; jq < 4; ++jq){
      int kb = k0 + skg*16 + jq*4;
      float f0 = W_V1[(size_t)(kb+0)*Vn + bnc];
      float f1 = W_V1[(size_t)(kb+1)*Vn + bnc];
      float f2 = W_V1[(size_t)(kb+2)*Vn + bnc];
      float f3 = W_V1[(size_t)(kb+3)*Vn + bnc];
      ushort4 u; u.x = f2bf(f0); u.y = f2bf(f1); u.z = f2bf(f2); u.w = f2bf(f3);
      *(ushort4*)&Bs[sn][skg*16 + jq*4] = u;
    }
    __syncthreads();
    #pragma unroll
    for (int kk = 0; kk < 2; ++kk){
      bf16x8 a[4], b;
      #pragma unroll
      for (int i = 0; i < 4; ++i)
        a[i] = *(const bf16x8*)&As[i*16 + lr][kk*32 + lq*8];
      b = *(const bf16x8*)&Bs[w*16 + lr][kk*32 + lq*8];
      #pragma unroll
      for (int mt = 0; mt < 4; ++mt)
        acc[mt] = __builtin_amdgcn_mfma_f32_16x16x32_bf16(a[mt], b, acc[mt], 0, 0, 0);
    }
  }

  const int n = n0 + w*16 + lr;
  const bool nok = (n < Vn);
  const float bb = nok ? b_V1[n] : 0.f;

  #pragma unroll
  for (int mt = 0; mt < 4; ++mt)
    #pragma unroll
    for (int v = 0; v < 4; ++v){
      int m = mt*16 + lq*4 + v;
      float val = nok ? (acc[mt][v] + bb) : -1e30f;
      if (nok) logits[(size_t)m*Vn + n] = val;
      float t = val;
      t = fmaxf(t, __shfl_xor(t,1)); t = fmaxf(t, __shfl_xor(t,2));
      t = fmaxf(t, __shfl_xor(t,4)); t = fmaxf(t, __shfl_xor(t,8));
      if (lr == 0) pred[w][m] = t;
    }
  __syncthreads();
  if (tid < 64)
    gmax[tid] = fmaxf(fmaxf(pred[0][tid], pred[1][tid]), fmaxf(pred[2][tid], pred[3][tid]));
  __syncthreads();

  #pragma unroll
  for (int mt = 0; mt < 4; ++mt)
    #pragma unroll
    for (int v = 0; v < 4; ++v){
      int m = mt*16 + lq*4 + v;
      float e = nok ? __expf(acc[mt][v] + bb - gmax[m]) : 0.f;
      e += __shfl_xor(e,1); e += __shfl_xor(e,2);
      e += __shfl_xor(e,4); e += __shfl_xor(e,8);
      if (lr == 0) pred[w][m] = e;
    }
  __syncthreads();
  if (tid < 64){
    float s = pred[0][tid] + pred[1][tid] + pred[2][tid] + pred[3][tid];
    mpart[(size_t)tid*782 + blockIdx.x] = gmax[tid];
    spart[(size_t)tid*782 + blockIdx.x] = s;
  }
}

// combine partials, write probs for a 6250-col slice, then scatter this chunk's indices  [verified]
__global__ __launch_bounds__(1024) void k_softmax_scatter(const float* __restrict__ logits,
                                                          const float* __restrict__ mpart, const float* __restrict__ spart,
                                                          const float* __restrict__ p_gen,
                                                          const int* __restrict__ ebev, const float* __restrict__ at_ws,
                                                          float* __restrict__ final_out){
  int b = blockIdx.y, ch = blockIdx.x, tid = threadIdx.x;
  __shared__ float red[1024];
  float mv = (tid < 782) ? mpart[(size_t)b*782 + tid] : -1e30f;
  red[tid] = mv; __syncthreads();
  for (int s = 512; s > 0; s >>= 1){ if (tid < s) red[tid] = fmaxf(red[tid], red[tid+s]); __syncthreads(); }
  float M = red[0]; __syncthreads();
  float sv = (tid < 782) ? spart[(size_t)b*782 + tid] * __expf(mv - M) : 0.f;
  red[tid] = sv; __syncthreads();
  for (int s = 512; s > 0; s >>= 1){ if (tid < s) red[tid] += red[tid+s]; __syncthreads(); }
  float pgb = p_gen[b];
  float scale = pgb/red[0];
  const float* lrow = &logits[(size_t)b*Vn];
  float* frow = &final_out[(size_t)b*VEXTn];
  int v0 = ch*6250;
  for (int v = v0 + tid; v < v0 + 6250; v += 1024) frow[v] = __expf(lrow[v] - M)*scale;
  if (ch == 7)
    for (int v = Vn + tid; v < VEXTn; v += 1024) frow[v] = 0.f;
  __syncthreads();
  int hi = (ch == 7) ? VEXTn : (v0 + 6250);
  if (tid < 400){
    int idx = ebev[b*400+tid];
    if (idx >= v0 && idx < hi){
      float add = (1.f - pgb) * at_ws[b*400+tid];
      atomicAdd(&frow[idx], add);
    }
  }
}

extern "C" void kernel_launch(void* const* d_in, const int* in_sizes, int n_in,
                              void* d_out, int out_size, void* d_ws, size_t ws_size,
                              hipStream_t stream)
{
  const float* x_t    = (const float*)d_in[0];
  const float* s_h    = (const float*)d_in[1];
  const float* s_c    = (const float*)d_in[2];
  const float* enc    = (const float*)d_in[3];
  const float* mask   = (const float*)d_in[4];
  const float* ct_e   = (const float*)d_in[5];
  const float* sumts  = (const float*)d_in[7];
  const float* prev_s = (const float*)d_in[8];
  const int*   ebev   = (const int*)d_in[9];
  const float* W_xc   = (const float*)d_in[10];
  const float* b_xc   = (const float*)d_in[11];
  const float* W_ih   = (const float*)d_in[12];
  const float* W_hh   = (const float*)d_in[13];
  const float* b_ih   = (const float*)d_in[14];
  const float* b_hh   = (const float*)d_in[15];
  const float* We_h   = (const float*)d_in[16];
  const float* We_s   = (const float*)d_in[17];
  const float* be_s   = (const float*)d_in[18];
  const float* ve     = (const float*)d_in[19];
  const float* Ws_h   = (const float*)d_in[20];
  const float* bs_h   = (const float*)d_in[21];
  const float* vs1    = (const float*)d_in[22];
  const float* vs2    = (const float*)d_in[23];
  const float* Wd_prev= (const float*)d_in[24];
  const float* Wd_s   = (const float*)d_in[25];
  const float* bd_s   = (const float*)d_in[26];
  const float* vd     = (const float*)d_in[27];
  const float* w_pg_em  = (const float*)d_in[28];
  const float* w_pg_cte = (const float*)d_in[29];
  const float* w_pg_ctd = (const float*)d_in[30];
  const float* w_pg_st  = (const float*)d_in[31];
  const float* b_pg_st  = (const float*)d_in[32];
  const float* W_V    = (const float*)d_in[33];
  const float* b_V    = (const float*)d_in[34];
  const float* W_V1   = (const float*)d_in[35];
  const float* b_V1   = (const float*)d_in[36];
  (void)in_sizes; (void)n_in; (void)out_size; (void)ws_size;

  float* out = (float*)d_out;
  float* o_final = out;
  float* o_h     = out + 3206400;
  float* o_c     = out + 3239168;
  float* o_cte   = out + 3271936;
  float* o_au    = out + 3337472;
  float* o_et2   = out + 3363072;
  float* o_sumn  = out + 3428608;
  float* o_prevs = out + 3454208;

  char* ws = (char*)d_ws;
  // memset-zeroed atomic accumulators [0, 1581056)
  float* et_raw    = (float*)(ws + 0);          // 102400
  float* au_raw    = (float*)(ws + 102400);     // 102400
  float* et2_acc   = (float*)(ws + 204800);     // 262144
  float* ov_acc    = (float*)(ws + 466944);     // 131072
  float* x_acc     = (float*)(ws + 598016);     // 65536
  float* gates_acc = (float*)(ws + 663552);     // 524288
  float* qe_acc    = (float*)(ws + 1187840);    // 262144
  float* qd_acc    = (float*)(ws + 1449984);    // 131072 -> memset end 1581056
  // scratch
  float* at_ws   = (float*)(ws + 1581056);      // 102400
  float* ct_d    = (float*)(ws + 1683456);      // 131072
  float* p_gen   = (float*)(ws + 1814528);      // 4096
  float* tmp_ed  = (float*)(ws + 1818624);      // 6553600 -> 8372224
  float* mpart   = (float*)(ws + 8372224);      // 200192
  float* spart   = (float*)(ws + 8572416);      // 200192 -> 8772608
  unsigned short* enc_bf = (unsigned short*)(ws + 8772608);   // 52428800 -> 61201408
  float* logits  = (float*)(ws + 8772608);      // 12.8MB, overlays enc_bf AFTER cte (last reader)
  unsigned short* Bt_bf  = (unsigned short*)(ws + 61201408);  // 4194304 -> 65395712

  hipMemsetAsync(ws, 0, 1581056, stream);
  k_front<<<34368, 256, 0, stream>>>(enc, enc_bf, We_h, Ws_h, Bt_bf,
                                     x_t, ct_e, W_xc, x_acc, prev_s, o_prevs);
  k_gates<<<1536, 256, 0, stream>>>(x_acc, b_xc, s_h, W_ih, W_hh, gates_acc);
  k_lstm<<<128, 256, 0, stream>>>(gates_acc, b_ih, b_hh, s_c, o_h, o_c, o_prevs);
  k_qq<<<1536, 256, 0, stream>>>(o_h, o_c, We_s, qe_acc, Wd_s, qd_acc, W_V, ov_acc);
  k_gemm_big<<<3456, 256, 0, stream>>>(enc_bf, Bt_bf, qe_acc, be_s, bs_h, ve, vs1, vs2,
                                       et_raw, au_raw, et2_acc,
                                       prev_s, Wd_prev, qd_acc, bd_s, vd, tmp_ed);
  k_attn_norm<<<64, 512, 0, stream>>>(et_raw, au_raw, et2_acc, sumts, mask, o_sumn, o_au, o_et2, at_ws);
  k_cte_ov<<<640, 256, 0, stream>>>(enc_bf, at_ws, o_cte, o_et2, W_V, ov_acc);
  k_ctd_ov<<<320, 512, 0, stream>>>(tmp_ed, prev_s, o_cte, o_et2, o_h, o_c,
                                    w_pg_cte, w_pg_ctd, w_pg_st, w_pg_em, b_pg_st,
                                    W_V, ct_d, p_gen, ov_acc);
  k_logits_mfma<<<782, 256, 0, stream>>>(ov_acc, b_V, W_V1, b_V1, logits, mpart, spart);
  k_softmax_scatter<<<dim3(8,64), 1024, 0, stream>>>(logits, mpart, spart, p_gen, ebev, at_ws, o_final);
}

// Round 7
// 685.938 us; speedup vs baseline: 1.5255x; 1.0756x over previous
//
#include <hip/hip_runtime.h>
#include <stdint.h>

#define Bn 64
#define Tn 400
#define Hn 512
#define En 256
#define Vn 50000
#define NOOVn 100
#define TPn 50
#define H2n 1024
#define VEXTn (Vn+NOOVn)  // 50100

typedef __bf16 bf16x8 __attribute__((ext_vector_type(8)));
typedef float  f32x4  __attribute__((ext_vector_type(4)));

__device__ __forceinline__ float sigf(float x){ return 1.0f/(1.0f+__expf(-x)); }
__device__ __forceinline__ float tanh_fast(float x){
  float e = __expf(2.0f*x);
  return (e-1.0f)/(e+1.0f);
}

__device__ __forceinline__ unsigned short f2bf(float f){
  union { float f; uint32_t u; } v; v.f = f;
  uint32_t r = v.u + 0x7FFFu + ((v.u >> 16) & 1u);
  return (unsigned short)(r >> 16);
}
__device__ __forceinline__ float bf2f(unsigned short s){
  union { uint32_t u; float f; } v; v.u = ((uint32_t)s) << 16;
  return v.f;
}

__device__ __forceinline__ void async16(const void* g, void* l){
  __builtin_amdgcn_global_load_lds((__attribute__((address_space(1))) void*)g,
                                   (__attribute__((address_space(3))) void*)l, 16, 0, 0);
}

// ---------------- front mega-launch ----------------
// [0,320): gemv_x split-K (K=256, atomics)
// [320,25920): enc fp32->bf16
// [25920,27968): Bt[n][k] = W[k][n] transpose+convert (We_h | Ws_h)
// [27968,28224): WdT[n][k] = Wd_prev[k][n] transpose+convert (for ed MFMA)
// [28224,29824): prev_s fp32->bf16 (ps_bf, for ed MFMA A-operand)
// [29824,36224): prev_s copy (tau<50) into o_prevs [64][51][512]
__global__ __launch_bounds__(256) void k_front(const float* __restrict__ enc, unsigned short* __restrict__ enc_bf,
                                               const float* __restrict__ W1, const float* __restrict__ W2,
                                               unsigned short* __restrict__ Bt,
                                               const float* __restrict__ Wd_prev, unsigned short* __restrict__ WdT_bf,
                                               unsigned short* __restrict__ ps_bf,
                                               const float* __restrict__ x_t, const float* __restrict__ ct_e,
                                               const float* __restrict__ W_xc, float* __restrict__ x_acc,
                                               const float* __restrict__ prev_s, float* __restrict__ o_prevs){
  __shared__ float tile[32][33];
  const int bx = blockIdx.x, tid = threadIdx.x;
  if (bx < 320){
    int z = bx >> 6, b = bx & 63;
    int n = tid, k0 = z*256;
    float acc = 0.f;
    #pragma unroll 4
    for (int kk = 0; kk < 256; ++kk){
      int k = k0 + kk;
      float a = (k < 256) ? x_t[b*256+k] : ct_e[b*1024 + k - 256];
      acc += a * W_xc[(size_t)k*256 + n];
    }
    atomicAdd(&x_acc[b*256+n], acc);
    return;
  }
  if (bx < 25920){
    int i = (bx - 320)*256 + tid;
    float4 v = ((const float4*)enc)[i];
    ushort4 r;
    r.x = f2bf(v.x); r.y = f2bf(v.y); r.z = f2bf(v.z); r.w = f2bf(v.w);
    ((ushort4*)enc_bf)[i] = r;
    return;
  }
  if (bx < 27968){
    int t = bx - 25920;
    const float* W = (t >> 10) ? W2 : W1;
    int nbase = (t >> 10) * 1024;
    int rem = t & 1023;
    int n0 = (rem & 31)*32, k0 = (rem >> 5)*32;
    int tx = tid & 31, ty = tid >> 5;
    for (int i = 0; i < 32; i += 8)
      tile[ty+i][tx] = W[(size_t)(k0+ty+i)*1024 + n0+tx];
    __syncthreads();
    for (int i = 0; i < 32; i += 8)
      Bt[(size_t)(nbase+n0+ty+i)*1024 + k0+tx] = f2bf(tile[tx][ty+i]);
    return;
  }
  if (bx < 28224){
    int t2 = bx - 27968;                 // [0,256): 16x16 tiles of 32x32
    int n0 = (t2 & 15)*32, k0 = (t2 >> 4)*32;
    int tx = tid & 31, ty = tid >> 5;
    for (int i = 0; i < 32; i += 8)
      tile[ty+i][tx] = Wd_prev[(size_t)(k0+ty+i)*512 + n0+tx];
    __syncthreads();
    for (int i = 0; i < 32; i += 8)
      WdT_bf[(size_t)(n0+ty+i)*512 + k0+tx] = f2bf(tile[tx][ty+i]);
    return;
  }
  if (bx < 29824){
    int i = (bx - 28224)*256 + tid;      // [0, 409600) float4s
    float4 v = ((const float4*)prev_s)[i];
    ushort4 r;
    r.x = f2bf(v.x); r.y = f2bf(v.y); r.z = f2bf(v.z); r.w = f2bf(v.w);
    ((ushort4*)ps_bf)[i] = r;
    return;
  }
  {
    int i = (bx - 29824)*256 + tid;      // [0, 1638400)
    int b = i / 25600;
    int rem = i - b*25600;               // tau*512 + j
    o_prevs[((size_t)b*51)*512 + rem] = prev_s[i];
  }
}

// gates split-K (z 0..2, K=256, atomics)
__global__ __launch_bounds__(256) void k_gates(const float* __restrict__ x_acc, const float* __restrict__ b_xc,
                                               const float* __restrict__ s_h,
                                               const float* __restrict__ W_ih, const float* __restrict__ W_hh,
                                               float* __restrict__ gates_acc){
  int x = blockIdx.x & 7;
  int rem = blockIdx.x >> 3;
  int b = rem & 63, z = rem >> 6;        // z 0..2
  int n = x*256 + threadIdx.x;
  int k0 = z*256;
  float acc = 0.f;
  #pragma unroll 4
  for (int kk = 0; kk < 256; ++kk){
    int k = k0 + kk;
    float a; const float* wrow;
    if (k < 256){ a = x_acc[b*256+k] + b_xc[k]; wrow = &W_ih[(size_t)k*2048]; }
    else        { a = s_h[b*512 + k-256];       wrow = &W_hh[(size_t)(k-256)*2048]; }
    acc += a * wrow[n];
  }
  atomicAdd(&gates_acc[(size_t)b*2048 + n], acc);
}

// lstm activations + h-append to o_prevs tail
__global__ __launch_bounds__(256) void k_lstm(const float* __restrict__ gates_acc,
                                              const float* __restrict__ b_ih, const float* __restrict__ b_hh,
                                              const float* __restrict__ s_c,
                                              float* __restrict__ h_out, float* __restrict__ c_out,
                                              float* __restrict__ o_prevs){
  int b = blockIdx.x >> 1;
  int j = (blockIdx.x & 1)*256 + threadIdx.x;
  const float* g = &gates_acc[(size_t)b*2048];
  float gi = g[j]      + b_ih[j]      + b_hh[j];
  float gf = g[512+j]  + b_ih[512+j]  + b_hh[512+j];
  float gg = g[1024+j] + b_ih[1024+j] + b_hh[1024+j];
  float go = g[1536+j] + b_ih[1536+j] + b_hh[1536+j];
  float c = sigf(gf)*s_c[b*512+j] + sigf(gi)*tanh_fast(gg);
  float h = sigf(go)*tanh_fast(c);
  h_out[b*512+j] = h;
  c_out[b*512+j] = c;
  o_prevs[((size_t)b*51 + 50)*512 + j] = h;
}

// qe + qd + outvec z0, all split-K-256 with atomics
// [0,1024): qe; [1024,1280): qd; [1280,1536): ov z0
__global__ __launch_bounds__(256) void k_qq(const float* __restrict__ h, const float* __restrict__ c,
                                            const float* __restrict__ We_s, float* __restrict__ qe_acc,
                                            const float* __restrict__ Wd_s, float* __restrict__ qd_acc,
                                            const float* __restrict__ W_V, float* __restrict__ ov_acc){
  const int bx = blockIdx.x, tid = threadIdx.x;
  if (bx < 1024){
    int x = bx & 3, b = (bx >> 2) & 63, z = bx >> 8;
    int n = x*256 + tid, k0 = z*256;
    float acc = 0.f;
    #pragma unroll 4
    for (int kk = 0; kk < 256; ++kk){
      int k = k0 + kk;
      float a = (k < 512) ? h[b*512+k] : c[b*512 + k-512];
      acc += a * We_s[(size_t)k*1024 + n];
    }
    atomicAdd(&qe_acc[b*1024+n], acc);
  } else if (bx < 1280){
    int j = bx - 1024;
    int x = j & 1, b = (j >> 1) & 63, z = j >> 7;
    int n = x*256 + tid, k0 = z*256;
    float acc = 0.f;
    #pragma unroll 4
    for (int kk = 0; kk < 256; ++kk){
      int k = k0 + kk;
      acc += h[b*512+k] * Wd_s[(size_t)k*512 + n];
    }
    atomicAdd(&qd_acc[b*512+n], acc);
  } else {
    int j = bx - 1280;
    int x = j & 1, b = (j >> 1) & 63, kh = j >> 7;
    int n = x*256 + tid, k0 = kh*256;
    float acc = 0.f;
    #pragma unroll 4
    for (int kk = 0; kk < 256; ++kk){
      int k = k0 + kk;
      acc += h[b*512+k] * W_V[(size_t)k*512 + n];    // z=0 rows [0,512)
    }
    atomicAdd(&ov_acc[b*512+n], acc);
  }
}

// ---------------- the big fused dual-GEMM + ed MFMA tiles ----------------
// [0,100): ed MFMA tiles: tmp_ed[3200][512] = tanh(ps_bf @ WdT_bf^T + qd+bd) * vd
//          (replaces the 256 VALU-bound ed blocks whose ~26us serial head delayed the grid)
// [100,3300): 128^2 main tiles, bijective XCD swizzle, verified epilogue.
__global__ __launch_bounds__(256,4) void k_gemm_big(
    const unsigned short* __restrict__ Abf,   // [25600][1024]
    const unsigned short* __restrict__ Btbf,  // [2048][1024]
    const float* __restrict__ q_e,
    const float* __restrict__ be_s,
    const float* __restrict__ bs_h, const float* __restrict__ ve,
    const float* __restrict__ vs1,  const float* __restrict__ vs2,
    float* __restrict__ et_raw, float* __restrict__ au_raw, float* __restrict__ et2_acc,
    const unsigned short* __restrict__ ps_bf,   // [3200][512] bf16
    const unsigned short* __restrict__ WdT_bf,  // [512][512]  bf16 (Wd_prev^T)
    const float* __restrict__ q_d, const float* __restrict__ bd_s,
    const float* __restrict__ vd, float* __restrict__ tmp_ed)
{
  __shared__ __align__(16) unsigned short As[128*64];
  __shared__ __align__(16) unsigned short Bs[128*64];
  __shared__ float bias2_s[2][128];
  __shared__ float vv_s[128];
  __shared__ float rowW_s[128];
  __shared__ unsigned char rowSel_s[128];

  const int tid = threadIdx.x;
  const int linb = blockIdx.x;
  const int w = tid >> 6, lane = tid & 63;
  const int wm = w & 1, wn = w >> 1;
  const int lr = lane & 15, lq = lane >> 4;
  const int srow = lane >> 3;
  const int c_g  = (lane & 7) ^ (srow & 7);

  f32x4 acc[4][4];
  #pragma unroll
  for (int i = 0; i < 4; ++i)
    #pragma unroll
    for (int j = 0; j < 4; ++j){ acc[i][j][0]=0.f; acc[i][j][1]=0.f; acc[i][j][2]=0.f; acc[i][j][3]=0.f; }

  if (linb < 100){
    // ---- ed MFMA tile: M-tile r0e, N-tile n0e, K=512 ----
    const int r0e = (linb >> 2)*128;             // 25 m-tiles over 3200 rows (b*50+tau)
    const int n0e = (linb & 3)*128;              // 4 n-tiles over 512
    const int b_base = r0e/50;
    if (tid < 128){
      int row = r0e + tid;
      rowSel_s[tid] = (unsigned char)(row/50 - b_base);   // 0..2
      rowW_s[tid]   = vd[n0e+tid];
      int cidx = n0e + tid;
      float bdc = bd_s[cidx];
      bias2_s[0][tid] = q_d[min(b_base+0,63)*512 + cidx] + bdc;
      bias2_s[1][tid] = q_d[min(b_base+1,63)*512 + cidx] + bdc;
      vv_s[tid]       = q_d[min(b_base+2,63)*512 + cidx] + bdc;
    }
    const unsigned short* gA0 = ps_bf  + (size_t)(r0e + w*32 + srow)*512 + c_g*8;
    const unsigned short* gB0 = WdT_bf + (size_t)(n0e + w*32 + srow)*512 + c_g*8;
    unsigned short* lA0 = As + w*32*64;
    unsigned short* lB0 = Bs + w*32*64;

    for (int kt = 0; kt < 8; ++kt){
      __syncthreads();
      #pragma unroll
      for (int q = 0; q < 4; ++q){
        async16(gA0 + (size_t)q*8*512 + kt*64, lA0 + q*512);
        async16(gB0 + (size_t)q*8*512 + kt*64, lB0 + q*512);
      }
      __syncthreads();
      #pragma unroll
      for (int kk = 0; kk < 2; ++kk){
        const int slot8 = ((kk*4 + lq) ^ (lr & 7)) * 8;
        bf16x8 a[4], b[4];
        #pragma unroll
        for (int i = 0; i < 4; ++i){
          a[i] = *(const bf16x8*)&As[(wm*64 + i*16 + lr)*64 + slot8];
          b[i] = *(const bf16x8*)&Bs[(wn*64 + i*16 + lr)*64 + slot8];
        }
        #pragma unroll
        for (int mt = 0; mt < 4; ++mt)
          #pragma unroll
          for (int nt = 0; nt < 4; ++nt)
            acc[mt][nt] = __builtin_amdgcn_mfma_f32_16x16x32_bf16(a[mt], b[nt], acc[mt][nt], 0, 0, 0);
      }
    }

    #pragma unroll
    for (int mt = 0; mt < 4; ++mt){
      #pragma unroll
      for (int v = 0; v < 4; ++v){
        int row = wm*64 + mt*16 + lq*4 + v;
        int sel = rowSel_s[row];
        #pragma unroll
        for (int nt = 0; nt < 4; ++nt){
          int col = wn*64 + nt*16 + lr;
          float qv = (sel == 0) ? bias2_s[0][col] : ((sel == 1) ? bias2_s[1][col] : vv_s[col]);
          tmp_ed[(size_t)(r0e+row)*512 + n0e + col] = tanh_fast(acc[mt][nt][v] + qv) * rowW_s[col];
        }
      }
    }
    return;
  }

  const int g = linb - 100;                       // 0..3199 = 8*400
  const int swz = (g & 7)*400 + (g >> 3);         // bijective XCD chunk swizzle
  const int bn = swz & 15, bm = swz >> 4;

  const int r0  = bm*128;
  const int n0g = bn*128;
  const bool etmode = (n0g < 1024);
  const int dbase = etmode ? n0g : (n0g - 1024);
  const int b_lo = r0/400;
  const int b_hi = min(b_lo+1, 63);
  const bool bcross = (r0/400) != ((r0+127)/400);

  if (tid < 128){
    int r = r0 + tid;
    int bb = r/400;
    rowSel_s[tid] = (unsigned char)(bb - b_lo);
    rowW_s[tid]   = vs2[r - bb*400];
    vv_s[tid]     = etmode ? ve[dbase+tid] : vs1[dbase+tid];
    bias2_s[0][tid] = etmode ? (q_e[b_lo*1024 + dbase + tid] + be_s[dbase+tid]) : bs_h[dbase+tid];
    bias2_s[1][tid] = etmode ? (q_e[b_hi*1024 + dbase + tid] + be_s[dbase+tid]) : bs_h[dbase+tid];
  }

  const unsigned short* gA0 = Abf  + (size_t)(r0  + w*32 + srow)*1024 + c_g*8;
  const unsigned short* gB0 = Btbf + (size_t)(n0g + w*32 + srow)*1024 + c_g*8;
  unsigned short* lA0 = As + w*32*64;
  unsigned short* lB0 = Bs + w*32*64;

  for (int kt = 0; kt < 16; ++kt){
    __syncthreads();
    #pragma unroll
    for (int q = 0; q < 4; ++q){
      async16(gA0 + (size_t)q*8*1024 + kt*64, lA0 + q*512);
      async16(gB0 + (size_t)q*8*1024 + kt*64, lB0 + q*512);
    }
    __syncthreads();
    #pragma unroll
    for (int kk = 0; kk < 2; ++kk){
      const int slot8 = ((kk*4 + lq) ^ (lr & 7)) * 8;
      bf16x8 a[4], b[4];
      #pragma unroll
      for (int i = 0; i < 4; ++i){
        a[i] = *(const bf16x8*)&As[(wm*64 + i*16 + lr)*64 + slot8];
        b[i] = *(const bf16x8*)&Bs[(wn*64 + i*16 + lr)*64 + slot8];
      }
      #pragma unroll
      for (int mt = 0; mt < 4; ++mt)
        #pragma unroll
        for (int nt = 0; nt < 4; ++nt)
          acc[mt][nt] = __builtin_amdgcn_mfma_f32_16x16x32_bf16(a[mt], b[nt], acc[mt][nt], 0, 0, 0);
    }
  }

  // ---- register epilogue ----
  float vvr[4], bias0[4], bias1[4];
  #pragma unroll
  for (int nt = 0; nt < 4; ++nt){
    int n = wn*64 + nt*16 + lr;
    vvr[nt]   = vv_s[n];
    bias0[nt] = bias2_s[0][n];
    bias1[nt] = bias2_s[1][n];
  }

  float rowdot[16];
  float colacc[4][2];
  #pragma unroll
  for (int nt = 0; nt < 4; ++nt){ colacc[nt][0]=0.f; colacc[nt][1]=0.f; }

  #pragma unroll
  for (int mt = 0; mt < 4; ++mt){
    #pragma unroll
    for (int v = 0; v < 4; ++v){
      int m = wm*64 + mt*16 + lq*4 + v;
      int sel = rowSel_s[m];
      float rw = rowW_s[m];
      float rd = 0.f;
      #pragma unroll
      for (int nt = 0; nt < 4; ++nt){
        float t = tanh_fast(acc[mt][nt][v] + (sel ? bias1[nt] : bias0[nt]));
        rd += t * vvr[nt];
        if (!etmode) colacc[nt][sel] += t * rw;
      }
      rowdot[mt*4+v] = rd;
    }
  }

  #pragma unroll
  for (int i = 0; i < 16; ++i){
    float s = rowdot[i];
    s += __shfl_xor(s,1); s += __shfl_xor(s,2); s += __shfl_xor(s,4); s += __shfl_xor(s,8);
    rowdot[i] = s;
  }
  if (lr == 0){
    float* dst = etmode ? et_raw : au_raw;
    #pragma unroll
    for (int i = 0; i < 16; ++i){
      int m = wm*64 + (i>>2)*16 + lq*4 + (i&3);
      atomicAdd(&dst[r0+m], rowdot[i]);
    }
  }

  if (!etmode){
    #pragma unroll
    for (int nt = 0; nt < 4; ++nt){
      #pragma unroll
      for (int s = 0; s < 2; ++s){
        float c = colacc[nt][s];
        c += __shfl_xor(c,16); c += __shfl_xor(c,32);
        if (lq == 0 && (s == 0 || bcross)){
          int n = wn*64 + nt*16 + lr;
          atomicAdd(&et2_acc[(b_lo+s)*1024 + dbase + n], c);
        }
      }
    }
  }
}

// ---------------- attention normalizations ----------------
__global__ __launch_bounds__(512) void k_attn_norm(const float* __restrict__ et_raw, const float* __restrict__ au_raw,
                                                   const float* __restrict__ et2_acc,
                                                   const float* __restrict__ sumts, const float* __restrict__ mask,
                                                   float* __restrict__ o_sumn, float* __restrict__ o_au,
                                                   float* __restrict__ o_et2, float* __restrict__ at_ws){
  int b = blockIdx.x, tid = threadIdx.x;
  __shared__ float red[512];
  float w = 0.f;
  if (tid < 400){
    float e  = __expf(et_raw[b*400+tid]);
    float st = sumts[b*400+tid];
    o_sumn[b*400+tid] = st + e;
    w = (e/st) * mask[b*400+tid];
  }
  red[tid] = w; __syncthreads();
  for (int s = 256; s > 0; s >>= 1){ if (tid < s) red[tid] += red[tid+s]; __syncthreads(); }
  float invw = 1.0f/red[0];
  __syncthreads();
  if (tid < 400) at_ws[b*400+tid] = w*invw;

  float a = 0.f;
  if (tid < 400) a = sigf(au_raw[b*400+tid]) * mask[b*400+tid];
  red[tid] = a; __syncthreads();
  for (int s = 256; s > 0; s >>= 1){ if (tid < s) red[tid] += red[tid+s]; __syncthreads(); }
  float inva = 1.0f/red[0];
  if (tid < 400) o_au[b*400+tid] = a*inva;

  for (int d = tid; d < 1024; d += 512) o_et2[b*1024+d] = sigf(et2_acc[b*1024+d]);
}

// cte (+ outvec z4/z5, split-K-256)
__global__ __launch_bounds__(256) void k_cte_ov(const unsigned short* __restrict__ Abf, const float* __restrict__ at_ws,
                                                float* __restrict__ o_cte, const float* __restrict__ o_et2,
                                                const float* __restrict__ W_V, float* __restrict__ ov_acc){
  const int bx = blockIdx.x, tid = threadIdx.x;
  if (bx < 128){
    int x = bx & 1, b = bx >> 1;
    int d0 = (x*256 + tid)*2;
    float a0 = 0.f, a1 = 0.f;
    for (int t = 0; t < 400; ++t){
      float w = at_ws[b*400+t];
      uint32_t v = *(const uint32_t*)&Abf[((size_t)(b*400+t))*1024 + d0];
      a0 += w * bf2f((unsigned short)(v & 0xffffu));
      a1 += w * bf2f((unsigned short)(v >> 16));
    }
    float2 r; r.x = a0; r.y = a1;
    *(float2*)&o_cte[b*1024 + d0] = r;
    return;
  }
  int idx = bx - 128;                              // [0,512)
  int zz = idx >> 8;                               // z4 or z5
  int rem = idx & 255;
  int kh = rem >> 7;
  int j = rem & 127;
  int x = j & 1, b = j >> 1;
  int n = x*256 + tid;
  const float* base = &o_et2[b*1024 + zz*512];
  const float* wrow = &W_V[(size_t)(2048 + zz*512)*512];
  float acc = 0.f;
  #pragma unroll 4
  for (int kk = 0; kk < 256; ++kk){
    int k = kh*256 + kk;
    acc += base[k] * wrow[(size_t)k*512 + n];
  }
  atomicAdd(&ov_acc[b*512+n], acc);
}

// ctd + p_gen + outvec z3 (in-block) + outvec z1/z2 (split-K-256 siblings)
__global__ __launch_bounds__(512) void k_ctd_ov(const float* __restrict__ tmp_ed, const float* __restrict__ prev_s,
                                                const float* __restrict__ cte, const float* __restrict__ et2,
                                                const float* __restrict__ h, const float* __restrict__ c,
                                                const float* __restrict__ w_pg_cte, const float* __restrict__ w_pg_ctd,
                                                const float* __restrict__ w_pg_st, const float* __restrict__ w_pg_em,
                                                const float* __restrict__ b_pg_st,
                                                const float* __restrict__ W_V,
                                                float* __restrict__ ct_d, float* __restrict__ p_gen,
                                                float* __restrict__ ov_acc){
  const int bx = blockIdx.x, tid = threadIdx.x;
  if (bx >= 64){
    int idx = bx - 64;                             // [0,256)
    int zz = idx >> 7;                             // z1 or z2
    int kh = (idx >> 6) & 1;
    int b = idx & 63;
    const float* base = &cte[b*1024 + zz*512];
    const float* wrow = &W_V[(size_t)(512 + zz*512)*512];
    float acc = 0.f;
    #pragma unroll 4
    for (int kk = 0; kk < 256; ++kk){
      int k = kh*256 + kk;
      acc += base[k] * wrow[(size_t)k*512 + tid];
    }
    atomicAdd(&ov_acc[b*512+tid], acc);
    return;
  }
  int b = bx;
  __shared__ float ed_s[50];
  __shared__ float ad_s[50];
  __shared__ float ctd_s[512];
  __shared__ float red[512];
  if (tid < 400){
    int tau = tid >> 3, part = tid & 7;
    const float* tp = &tmp_ed[((size_t)b*50 + tau)*512 + part*64];
    float p = 0.f;
    for (int j = 0; j < 64; ++j) p += tp[j];
    p += __shfl_xor(p, 1); p += __shfl_xor(p, 2); p += __shfl_xor(p, 4);
    if (part == 0) ed_s[tau] = p;
  }
  __syncthreads();
  if (tid == 0){
    float mx = -1e30f;
    for (int t = 0; t < 50; ++t) mx = fmaxf(mx, ed_s[t]);
    float se = 0.f;
    for (int t = 0; t < 50; ++t){ float e = __expf(ed_s[t]-mx); ad_s[t] = e; se += e; }
    float inv = 1.f/se;
    for (int t = 0; t < 50; ++t) ad_s[t] *= inv;
  }
  __syncthreads();
  float acc = 0.f;
  for (int t = 0; t < 50; ++t) acc += ad_s[t]*prev_s[((size_t)b*50 + t)*512 + tid];
  ct_d[b*512+tid] = acc;
  ctd_s[tid] = acc;

  // p_gen partials
  float s = acc*w_pg_ctd[tid] + h[b*512+tid]*w_pg_st[tid] + c[b*512+tid]*w_pg_st[512+tid];
  s += cte[b*1024+tid]*w_pg_cte[tid] + cte[b*1024+512+tid]*w_pg_cte[512+tid];
  s += et2[b*1024+tid]*w_pg_em[tid]  + et2[b*1024+512+tid]*w_pg_em[512+tid];
  red[tid] = s; __syncthreads();
  for (int k = 256; k > 0; k >>= 1){ if (tid < k) red[tid] += red[tid+k]; __syncthreads(); }
  if (tid == 0) p_gen[b] = sigf(red[0] + b_pg_st[0]);

  // outvec z3 using in-LDS ct_d
  float accv = 0.f;
  #pragma unroll 4
  for (int k = 0; k < 512; ++k)
    accv += ctd_s[k] * W_V[(size_t)(1536 + k)*512 + tid];
  atomicAdd(&ov_acc[b*512+tid], accv);
}

// ---------------- logits MFMA (fused A-convert + softmax partials) ----------------
__global__ __launch_bounds__(256,4) void k_logits_mfma(const float* __restrict__ ov_acc,  // [64][512] fp32
                                                       const float* __restrict__ b_V,    // [512]
                                                       const float* __restrict__ W_V1,   // [512][50000] fp32
                                                       const float* __restrict__ b_V1, float* __restrict__ logits,
                                                       float* __restrict__ mpart, float* __restrict__ spart){
  __shared__ __align__(16) unsigned short As[64][72];
  __shared__ __align__(16) unsigned short Bs[64][72];
  __shared__ float pred[4][64];
  __shared__ float gmax[64];
  const int tid = threadIdx.x;
  const int n0 = blockIdx.x*64;
  const int w = tid >> 6, lane = tid & 63;
  const int lr = lane & 15, lq = lane >> 4;

  const int am = tid >> 2, ac = tid & 3;
  const int sn = tid & 63, skg = tid >> 6;
  const int bnc = (n0 + sn < Vn) ? (n0 + sn) : (Vn - 1);

  f32x4 acc[4];
  #pragma unroll
  for (int i = 0; i < 4; ++i){ acc[i][0]=0.f; acc[i][1]=0.f; acc[i][2]=0.f; acc[i][3]=0.f; }

  for (int kt = 0; kt < 8; ++kt){
    const int k0 = kt*64;
    __syncthreads();
    #pragma unroll
    for (int s = 0; s < 2; ++s){
      int ke = k0 + (ac + 4*s)*8;
      float4 fa  = *(const float4*)&ov_acc[am*512 + ke];
      float4 fa2 = *(const float4*)&ov_acc[am*512 + ke + 4];
      float4 fb  = *(const float4*)&b_V[ke];
      float4 fb2 = *(const float4*)&b_V[ke + 4];
      ushort4 u0, u1;
      u0.x = f2bf(fa.x+fb.x);  u0.y = f2bf(fa.y+fb.y);  u0.z = f2bf(fa.z+fb.z);  u0.w = f2bf(fa.w+fb.w);
      u1.x = f2bf(fa2.x+fb2.x); u1.y = f2bf(fa2.y+fb2.y); u1.z = f2bf(fa2.z+fb2.z); u1.w = f2bf(fa2.w+fb2.w);
      *(ushort4*)&As[am][(ac + 4*s)*8]     = u0;
      *(ushort4*)&As[am][(ac + 4*s)*8 + 4] = u1;
    }
    #pragma unroll
    for (int jq = 0; jq < 4; ++jq){
      int kb = k0 + skg*16 + jq*4;
      float f0 = W_V1[(size_t)(kb+0)*Vn + bnc];
      float f1 = W_V1[(size_t)(kb+1)*Vn + bnc];
      float f2 = W_V1[(size_t)(kb+2)*Vn + bnc];
      float f3 = W_V1[(size_t)(kb+3)*Vn + bnc];
      ushort4 u; u.x = f2bf(f0); u.y = f2bf(f1); u.z = f2bf(f2); u.w = f2bf(f3);
      *(ushort4*)&Bs[sn][skg*16 + jq*4] = u;
    }
    __syncthreads();
    #pragma unroll
    for (int kk = 0; kk < 2; ++kk){
      bf16x8 a[4], b;
      #pragma unroll
      for (int i = 0; i < 4; ++i)
        a[i] = *(const bf16x8*)&As[i*16 + lr][kk*32 + lq*8];
      b = *(const bf16x8*)&Bs[w*16 + lr][kk*32 + lq*8];
      #pragma unroll
      for (int mt = 0; mt < 4; ++mt)
        acc[mt] = __builtin_amdgcn_mfma_f32_16x16x32_bf16(a[mt], b, acc[mt], 0, 0, 0);
    }
  }

  const int n = n0 + w*16 + lr;
  const bool nok = (n < Vn);
  const float bb = nok ? b_V1[n] : 0.f;

  #pragma unroll
  for (int mt = 0; mt < 4; ++mt)
    #pragma unroll
    for (int v = 0; v < 4; ++v){
      int m = mt*16 + lq*4 + v;
      float val = nok ? (acc[mt][v] + bb) : -1e30f;
      if (nok) logits[(size_t)m*Vn + n] = val;
      float t = val;
      t = fmaxf(t, __shfl_xor(t,1)); t = fmaxf(t, __shfl_xor(t,2));
      t = fmaxf(t, __shfl_xor(t,4)); t = fmaxf(t, __shfl_xor(t,8));
      if (lr == 0) pred[w][m] = t;
    }
  __syncthreads();
  if (tid < 64)
    gmax[tid] = fmaxf(fmaxf(pred[0][tid], pred[1][tid]), fmaxf(pred[2][tid], pred[3][tid]));
  __syncthreads();

  #pragma unroll
  for (int mt = 0; mt < 4; ++mt)
    #pragma unroll
    for (int v = 0; v < 4; ++v){
      int m = mt*16 + lq*4 + v;
      float e = nok ? __expf(acc[mt][v] + bb - gmax[m]) : 0.f;
      e += __shfl_xor(e,1); e += __shfl_xor(e,2);
      e += __shfl_xor(e,4); e += __shfl_xor(e,8);
      if (lr == 0) pred[w][m] = e;
    }
  __syncthreads();
  if (tid < 64){
    float s = pred[0][tid] + pred[1][tid] + pred[2][tid] + pred[3][tid];
    mpart[(size_t)tid*782 + blockIdx.x] = gmax[tid];
    spart[(size_t)tid*782 + blockIdx.x] = s;
  }
}

// combine partials, write probs for a 6250-col slice, then scatter this chunk's indices
__global__ __launch_bounds__(1024) void k_softmax_scatter(const float* __restrict__ logits,
                                                          const float* __restrict__ mpart, const float* __restrict__ spart,
                                                          const float* __restrict__ p_gen,
                                                          const int* __restrict__ ebev, const float* __restrict__ at_ws,
                                                          float* __restrict__ final_out){
  int b = blockIdx.y, ch = blockIdx.x, tid = threadIdx.x;
  __shared__ float red[1024];
  float mv = (tid < 782) ? mpart[(size_t)b*782 + tid] : -1e30f;
  red[tid] = mv; __syncthreads();
  for (int s = 512; s > 0; s >>= 1){ if (tid < s) red[tid] = fmaxf(red[tid], red[tid+s]); __syncthreads(); }
  float M = red[0]; __syncthreads();
  float sv = (tid < 782) ? spart[(size_t)b*782 + tid] * __expf(mv - M) : 0.f;
  red[tid] = sv; __syncthreads();
  for (int s = 512; s > 0; s >>= 1){ if (tid < s) red[tid] += red[tid+s]; __syncthreads(); }
  float pgb = p_gen[b];
  float scale = pgb/red[0];
  const float* lrow = &logits[(size_t)b*Vn];
  float* frow = &final_out[(size_t)b*VEXTn];
  int v0 = ch*6250;
  for (int v = v0 + tid; v < v0 + 6250; v += 1024) frow[v] = __expf(lrow[v] - M)*scale;
  if (ch == 7)
    for (int v = Vn + tid; v < VEXTn; v += 1024) frow[v] = 0.f;
  __syncthreads();
  int hi = (ch == 7) ? VEXTn : (v0 + 6250);
  if (tid < 400){
    int idx = ebev[b*400+tid];
    if (idx >= v0 && idx < hi){
      float add = (1.f - pgb) * at_ws[b*400+tid];
      atomicAdd(&frow[idx], add);
    }
  }
}

extern "C" void kernel_launch(void* const* d_in, const int* in_sizes, int n_in,
                              void* d_out, int out_size, void* d_ws, size_t ws_size,
                              hipStream_t stream)
{
  const float* x_t    = (const float*)d_in[0];
  const float* s_h    = (const float*)d_in[1];
  const float* s_c    = (const float*)d_in[2];
  const float* enc    = (const float*)d_in[3];
  const float* mask   = (const float*)d_in[4];
  const float* ct_e   = (const float*)d_in[5];
  const float* sumts  = (const float*)d_in[7];
  const float* prev_s = (const float*)d_in[8];
  const int*   ebev   = (const int*)d_in[9];
  const float* W_xc   = (const float*)d_in[10];
  const float* b_xc   = (const float*)d_in[11];
  const float* W_ih   = (const float*)d_in[12];
  const float* W_hh   = (const float*)d_in[13];
  const float* b_ih   = (const float*)d_in[14];
  const float* b_hh   = (const float*)d_in[15];
  const float* We_h   = (const float*)d_in[16];
  const float* We_s   = (const float*)d_in[17];
  const float* be_s   = (const float*)d_in[18];
  const float* ve     = (const float*)d_in[19];
  const float* Ws_h   = (const float*)d_in[20];
  const float* bs_h   = (const float*)d_in[21];
  const float* vs1    = (const float*)d_in[22];
  const float* vs2    = (const float*)d_in[23];
  const float* Wd_prev= (const float*)d_in[24];
  const float* Wd_s   = (const float*)d_in[25];
  const float* bd_s   = (const float*)d_in[26];
  const float* vd     = (const float*)d_in[27];
  const float* w_pg_em  = (const float*)d_in[28];
  const float* w_pg_cte = (const float*)d_in[29];
  const float* w_pg_ctd = (const float*)d_in[30];
  const float* w_pg_st  = (const float*)d_in[31];
  const float* b_pg_st  = (const float*)d_in[32];
  const float* W_V    = (const float*)d_in[33];
  const float* b_V    = (const float*)d_in[34];
  const float* W_V1   = (const float*)d_in[35];
  const float* b_V1   = (const float*)d_in[36];
  (void)in_sizes; (void)n_in; (void)out_size; (void)ws_size;

  float* out = (float*)d_out;
  float* o_final = out;
  float* o_h     = out + 3206400;
  float* o_c     = out + 3239168;
  float* o_cte   = out + 3271936;
  float* o_au    = out + 3337472;
  float* o_et2   = out + 3363072;
  float* o_sumn  = out + 3428608;
  float* o_prevs = out + 3454208;

  char* ws = (char*)d_ws;
  // memset-zeroed atomic accumulators [0, 1581056)
  float* et_raw    = (float*)(ws + 0);          // 102400
  float* au_raw    = (float*)(ws + 102400);     // 102400
  float* et2_acc   = (float*)(ws + 204800);     // 262144
  float* ov_acc    = (float*)(ws + 466944);     // 131072
  float* x_acc     = (float*)(ws + 598016);     // 65536
  float* gates_acc = (float*)(ws + 663552);     // 524288
  float* qe_acc    = (float*)(ws + 1187840);    // 262144
  float* qd_acc    = (float*)(ws + 1449984);    // 131072 -> memset end 1581056
  // scratch
  float* at_ws   = (float*)(ws + 1581056);      // 102400
  float* ct_d    = (float*)(ws + 1683456);      // 131072
  float* p_gen   = (float*)(ws + 1814528);      // 4096
  float* tmp_ed  = (float*)(ws + 1818624);      // 6553600 -> 8372224
  float* mpart   = (float*)(ws + 8372224);      // 200192
  float* spart   = (float*)(ws + 8572416);      // 200192 -> 8772608
  unsigned short* enc_bf = (unsigned short*)(ws + 8772608);   // 52428800 -> 61201408
  float* logits  = (float*)(ws + 8772608);      // 12.8MB, overlays enc_bf AFTER cte (last reader)
  unsigned short* Bt_bf  = (unsigned short*)(ws + 61201408);  // 4194304 -> 65395712
  unsigned short* WdT_bf = (unsigned short*)(ws + 65395712);  // 524288  -> 65920000
  unsigned short* ps_bf  = (unsigned short*)(ws + 65920000);  // 3276800 -> 69196800

  hipMemsetAsync(ws, 0, 1581056, stream);
  k_front<<<36224, 256, 0, stream>>>(enc, enc_bf, We_h, Ws_h, Bt_bf,
                                     Wd_prev, WdT_bf, ps_bf,
                                     x_t, ct_e, W_xc, x_acc, prev_s, o_prevs);
  k_gates<<<1536, 256, 0, stream>>>(x_acc, b_xc, s_h, W_ih, W_hh, gates_acc);
  k_lstm<<<128, 256, 0, stream>>>(gates_acc, b_ih, b_hh, s_c, o_h, o_c, o_prevs);
  k_qq<<<1536, 256, 0, stream>>>(o_h, o_c, We_s, qe_acc, Wd_s, qd_acc, W_V, ov_acc);
  k_gemm_big<<<3300, 256, 0, stream>>>(enc_bf, Bt_bf, qe_acc, be_s, bs_h, ve, vs1, vs2,
                                       et_raw, au_raw, et2_acc,
                                       ps_bf, WdT_bf, qd_acc, bd_s, vd, tmp_ed);
  k_attn_norm<<<64, 512, 0, stream>>>(et_raw, au_raw, et2_acc, sumts, mask, o_sumn, o_au, o_et2, at_ws);
  k_cte_ov<<<640, 256, 0, stream>>>(enc_bf, at_ws, o_cte, o_et2, W_V, ov_acc);
  k_ctd_ov<<<320, 512, 0, stream>>>(tmp_ed, prev_s, o_cte, o_et2, o_h, o_c,
                                    w_pg_cte, w_pg_ctd, w_pg_st, w_pg_em, b_pg_st,
                                    W_V, ct_d, p_gen, ov_acc);
  k_logits_mfma<<<782, 256, 0, stream>>>(ov_acc, b_V, W_V1, b_V1, logits, mpart, spart);
  k_softmax_scatter<<<dim3(8,64), 1024, 0, stream>>>(logits, mpart, spart, p_gen, ebev, at_ws, o_final);
}